// Round 16
// baseline (24705.261 us; speedup 1.0000x reference)
//
#include <hip/hip_runtime.h>
#include <math.h>

#define D2T   16
#define CHI   96
#define NITER 12
#define KSUB  128
#define JSWMAX 12
#define NBRED 128

// ---------------- tiny builders ----------------
__global__ void k_symA(const float* __restrict__ A1, float* __restrict__ As) {
  int i = blockIdx.x * blockDim.x + threadIdx.x;
  if (i >= 128) return;
  int w = i % 4, x = (i / 4) % 4, u = (i / 16) % 4, p = i / 64;
#define AT(pp,aa,bb,cc) A1[(((pp)*4+(aa))*4+(bb))*4+(cc)]
  As[i] = AT(p,u,x,w) + AT(p,u,w,x) + AT(p,x,w,u) + AT(p,w,x,u) + AT(p,w,u,x) + AT(p,x,u,w);
#undef AT
}

__global__ void k_buildT(const float* __restrict__ As, float* __restrict__ T) {
  int i = blockIdx.x * blockDim.x + threadIdx.x;
  if (i >= 4096) return;
  int Wf = i % 16, Xf = (i / 16) % 16, Uf = i / 256;
  int u = Uf >> 2, a = Uf & 3, x = Xf >> 2, b = Xf & 3, w = Wf >> 2, c = Wf & 3;
  float s = 0.f;
  for (int p = 0; p < 2; ++p)
    s += As[((p*4+u)*4+x)*4+w] * As[((p*4+a)*4+b)*4+c];
  T[i] = s;
}

__global__ void k_buildM(const float* __restrict__ T, float* __restrict__ M) {
  int i = blockIdx.x * blockDim.x + threadIdx.x;
  if (i >= 65536) return;
  int y = i % 16, x = (i / 16) % 16, v = (i / 256) % 16, u = i / 4096;
  const float* Tu = T + (u*16 + x)*16;
  const float* Tv = T + (v*16 + y)*16;
  float s = 0.f;
  for (int w = 0; w < 16; ++w) s += Tu[w]*Tv[w];
  M[i] = s;
}

__global__ void k_initC(const float* __restrict__ M, float* __restrict__ C) {
  int i = blockIdx.x * blockDim.x + threadIdx.x;
  if (i >= 256) return;
  int v = i / 16, y = i % 16;
  float s = 0.f;
  for (int u = 0; u < 16; ++u)
    for (int x = 0; x < 16; ++x)
      s += M[((u*16+v)*16+x)*16+y];
  C[v*16+y] = s;
}

__global__ void k_initE(const float* __restrict__ M, float* __restrict__ E) {
  int i = blockIdx.x * blockDim.x + threadIdx.x;
  if (i >= 4096) return;
  int v = i % 16, y = (i / 16) % 16, u = i / 256;
  float s = 0.f;
  for (int x = 0; x < 16; ++x) s += M[((u*16+v)*16+x)*16+y];
  E[(u*16+y)*16+v] = s;   // E[u][y][v], chic=16
}

// ---------------- generic helpers ----------------
__global__ void k_perm4(const float* __restrict__ src, float* __restrict__ dst,
                        int d0, int d1, int d2, int d3,
                        long s0, long s1, long s2, long s3) {
  long n = (long)d0 * d1 * d2 * d3;
  for (long i = blockIdx.x * (long)blockDim.x + threadIdx.x; i < n;
       i += (long)gridDim.x * blockDim.x) {
    int i3 = (int)(i % d3); long t = i / d3;
    int i2 = (int)(t % d2); t /= d2;
    int i1 = (int)(t % d1); int i0 = (int)(t / d1);
    dst[i] = src[i0*s0 + i1*s1 + i2*s2 + i3*s3];
  }
}

__global__ void k_sym2d(float* __restrict__ A, int n) {
  long nn = (long)n * n;
  for (long i = blockIdx.x * (long)blockDim.x + threadIdx.x; i < nn;
       i += (long)gridDim.x * blockDim.x) {
    int r = (int)(i / n), c = (int)(i % n);
    if (r <= c) {
      float v = 0.5f * (A[(long)r*n + c] + A[(long)c*n + r]);
      A[(long)r*n + c] = v; A[(long)c*n + r] = v;
    }
  }
}

// fused: symmetrize E (a<=b pairs) AND accumulate ||E||^2 partials (off-diag counted twice)
__global__ void k_symE_sumsq(float* __restrict__ E, int chi, float* __restrict__ partial) {
  __shared__ float red[256];
  long n = (long)chi * 16 * chi;
  float s = 0.f;
  for (long i = blockIdx.x * (long)blockDim.x + threadIdx.x; i < n;
       i += (long)gridDim.x * blockDim.x) {
    int b = (int)(i % chi); long t = i / chi;
    int y = (int)(t % 16); int a = (int)(t / 16);
    if (a <= b) {
      long ia = ((long)a*16 + y)*chi + b, ib = ((long)b*16 + y)*chi + a;
      float v = 0.5f * (E[ia] + E[ib]);
      E[ia] = v; E[ib] = v;
      s += (a == b) ? v*v : 2.f*v*v;
    }
  }
  red[threadIdx.x] = s; __syncthreads();
  for (int o = 128; o; o >>= 1) { if ((int)threadIdx.x < o) red[threadIdx.x] += red[threadIdx.x + o]; __syncthreads(); }
  if (threadIdx.x == 0) partial[blockIdx.x] = red[0];
}

__global__ void k_sumsq(const float* __restrict__ a, long n, float* __restrict__ partial) {
  __shared__ float red[256];
  float s = 0.f;
  for (long i = blockIdx.x * 256L + threadIdx.x; i < n; i += (long)gridDim.x * 256L) {
    float v = a[i]; s += v*v;
  }
  red[threadIdx.x] = s; __syncthreads();
  for (int o = 128; o; o >>= 1) { if ((int)threadIdx.x < o) red[threadIdx.x] += red[threadIdx.x + o]; __syncthreads(); }
  if (threadIdx.x == 0) partial[blockIdx.x] = red[0];
}

__global__ void k_scale_sumsq(float* __restrict__ a, long n,
                              const float* __restrict__ partial, int nb) {
  __shared__ float red[256];
  float s = 0.f;
  for (int i = threadIdx.x; i < nb; i += 256) s += partial[i];
  red[threadIdx.x] = s; __syncthreads();
  for (int o = 128; o; o >>= 1) { if ((int)threadIdx.x < o) red[threadIdx.x] += red[threadIdx.x + o]; __syncthreads(); }
  float f = rsqrtf(red[0]);
  for (long i = blockIdx.x * (long)blockDim.x + threadIdx.x; i < n;
       i += (long)gridDim.x * blockDim.x) a[i] *= f;
}

// ---------------- GEMMs (fp32, 64x64 tile, 256 thr, 4x4/thr) ----------------
__global__ __launch_bounds__(256) void k_gemm_nn(const float* __restrict__ A, const float* __restrict__ B,
                                                 float* __restrict__ C, int M, int N, int K) {
  __shared__ float As[16][68];
  __shared__ float Bs[16][68];
  int tid = threadIdx.x, tx = tid % 16, ty = tid / 16;
  int row0 = blockIdx.y*64, col0 = blockIdx.x*64;
  float acc[4][4] = {};
  for (int k0 = 0; k0 < K; k0 += 16) {
    for (int i = tid; i < 16*64; i += 256) {
      int c = i % 16, r = i / 16;
      float v = 0.f;
      if (row0 + r < M && k0 + c < K) v = A[(long)(row0+r)*K + k0 + c];
      As[c][r] = v;
    }
    for (int i = tid; i < 16*64; i += 256) {
      int c = i % 64, r = i / 64;
      float v = 0.f;
      if (k0 + r < K && col0 + c < N) v = B[(long)(k0+r)*N + col0 + c];
      Bs[r][c] = v;
    }
    __syncthreads();
    for (int kk = 0; kk < 16; ++kk) {
      float av[4], bv[4];
#pragma unroll
      for (int ii = 0; ii < 4; ++ii) av[ii] = As[kk][ty*4+ii];
#pragma unroll
      for (int jj = 0; jj < 4; ++jj) bv[jj] = Bs[kk][tx*4+jj];
#pragma unroll
      for (int ii = 0; ii < 4; ++ii)
#pragma unroll
        for (int jj = 0; jj < 4; ++jj) acc[ii][jj] += av[ii]*bv[jj];
    }
    __syncthreads();
  }
  for (int ii = 0; ii < 4; ++ii) {
    int r = row0 + ty*4 + ii;
    if (r >= M) continue;
    for (int jj = 0; jj < 4; ++jj) {
      int c = col0 + tx*4 + jj;
      if (c < N) C[(long)r*N + c] = acc[ii][jj];
    }
  }
}

// nn GEMM with permuted output: dst = (r%Ra)*sa + (r/Ra)*sb + (c%Cb)*sc + (c/Cb)*sd
__global__ __launch_bounds__(256) void k_gemm_nn_p(const float* __restrict__ A, const float* __restrict__ B,
                                                   float* __restrict__ C, int M, int N, int K,
                                                   int Ra, long sa, long sb, int Cb, long sc, long sd) {
  __shared__ float As[16][68];
  __shared__ float Bs[16][68];
  int tid = threadIdx.x, tx = tid % 16, ty = tid / 16;
  int row0 = blockIdx.y*64, col0 = blockIdx.x*64;
  float acc[4][4] = {};
  for (int k0 = 0; k0 < K; k0 += 16) {
    for (int i = tid; i < 16*64; i += 256) {
      int c = i % 16, r = i / 16;
      float v = 0.f;
      if (row0 + r < M && k0 + c < K) v = A[(long)(row0+r)*K + k0 + c];
      As[c][r] = v;
    }
    for (int i = tid; i < 16*64; i += 256) {
      int c = i % 64, r = i / 64;
      float v = 0.f;
      if (k0 + r < K && col0 + c < N) v = B[(long)(k0+r)*N + col0 + c];
      Bs[r][c] = v;
    }
    __syncthreads();
    for (int kk = 0; kk < 16; ++kk) {
      float av[4], bv[4];
#pragma unroll
      for (int ii = 0; ii < 4; ++ii) av[ii] = As[kk][ty*4+ii];
#pragma unroll
      for (int jj = 0; jj < 4; ++jj) bv[jj] = Bs[kk][tx*4+jj];
#pragma unroll
      for (int ii = 0; ii < 4; ++ii)
#pragma unroll
        for (int jj = 0; jj < 4; ++jj) acc[ii][jj] += av[ii]*bv[jj];
    }
    __syncthreads();
  }
  for (int ii = 0; ii < 4; ++ii) {
    int r = row0 + ty*4 + ii;
    if (r >= M) continue;
    long ro = (long)(r % Ra)*sa + (long)(r / Ra)*sb;
    for (int jj = 0; jj < 4; ++jj) {
      int c = col0 + tx*4 + jj;
      if (c < N) C[ro + (long)(c % Cb)*sc + (long)(c / Cb)*sd] = acc[ii][jj];
    }
  }
}

// C = A^T B (sub=0) or C -= A^T B (sub=1); A is (K x M) row-major, B is (K x N) row-major
__global__ __launch_bounds__(256) void k_gemm_tn(const float* __restrict__ A, const float* __restrict__ B,
                                                 float* __restrict__ C, int M, int N, int K, int sub) {
  __shared__ float As[16][68];
  __shared__ float Bs[16][68];
  int tid = threadIdx.x, tx = tid % 16, ty = tid / 16;
  int row0 = blockIdx.y*64, col0 = blockIdx.x*64;
  float acc[4][4] = {};
  for (int k0 = 0; k0 < K; k0 += 16) {
    for (int i = tid; i < 16*64; i += 256) {
      int r = i % 64, kk = i / 64;
      float v = 0.f;
      if (k0 + kk < K && row0 + r < M) v = A[(long)(k0+kk)*M + row0 + r];
      As[kk][r] = v;
    }
    for (int i = tid; i < 16*64; i += 256) {
      int c = i % 64, kk = i / 64;
      float v = 0.f;
      if (k0 + kk < K && col0 + c < N) v = B[(long)(k0+kk)*N + col0 + c];
      Bs[kk][c] = v;
    }
    __syncthreads();
    for (int kk = 0; kk < 16; ++kk) {
      float av[4], bv[4];
#pragma unroll
      for (int ii = 0; ii < 4; ++ii) av[ii] = As[kk][ty*4+ii];
#pragma unroll
      for (int jj = 0; jj < 4; ++jj) bv[jj] = Bs[kk][tx*4+jj];
#pragma unroll
      for (int ii = 0; ii < 4; ++ii)
#pragma unroll
        for (int jj = 0; jj < 4; ++jj) acc[ii][jj] += av[ii]*bv[jj];
    }
    __syncthreads();
  }
  for (int ii = 0; ii < 4; ++ii) {
    int r = row0 + ty*4 + ii;
    if (r >= M) continue;
    for (int jj = 0; jj < 4; ++jj) {
      int c = col0 + tx*4 + jj;
      if (c < N) {
        if (sub) C[(long)r*N + c] -= acc[ii][jj];
        else     C[(long)r*N + c]  = acc[ii][jj];
      }
    }
  }
}

// tn GEMM with permuted output (same dst mapping as nn_p)
__global__ __launch_bounds__(256) void k_gemm_tn_p(const float* __restrict__ A, const float* __restrict__ B,
                                                   float* __restrict__ C, int M, int N, int K,
                                                   int Ra, long sa, long sb, int Cb, long sc, long sd) {
  __shared__ float As[16][68];
  __shared__ float Bs[16][68];
  int tid = threadIdx.x, tx = tid % 16, ty = tid / 16;
  int row0 = blockIdx.y*64, col0 = blockIdx.x*64;
  float acc[4][4] = {};
  for (int k0 = 0; k0 < K; k0 += 16) {
    for (int i = tid; i < 16*64; i += 256) {
      int r = i % 64, kk = i / 64;
      float v = 0.f;
      if (k0 + kk < K && row0 + r < M) v = A[(long)(k0+kk)*M + row0 + r];
      As[kk][r] = v;
    }
    for (int i = tid; i < 16*64; i += 256) {
      int c = i % 64, kk = i / 64;
      float v = 0.f;
      if (k0 + kk < K && col0 + c < N) v = B[(long)(k0+kk)*N + col0 + c];
      Bs[kk][c] = v;
    }
    __syncthreads();
    for (int kk = 0; kk < 16; ++kk) {
      float av[4], bv[4];
#pragma unroll
      for (int ii = 0; ii < 4; ++ii) av[ii] = As[kk][ty*4+ii];
#pragma unroll
      for (int jj = 0; jj < 4; ++jj) bv[jj] = Bs[kk][tx*4+jj];
#pragma unroll
      for (int ii = 0; ii < 4; ++ii)
#pragma unroll
        for (int jj = 0; jj < 4; ++jj) acc[ii][jj] += av[ii]*bv[jj];
    }
    __syncthreads();
  }
  for (int ii = 0; ii < 4; ++ii) {
    int r = row0 + ty*4 + ii;
    if (r >= M) continue;
    long ro = (long)(r % Ra)*sa + (long)(r / Ra)*sb;
    for (int jj = 0; jj < 4; ++jj) {
      int c = col0 + tx*4 + jj;
      if (c < N) C[ro + (long)(c % Cb)*sc + (long)(c / Cb)*sd] = acc[ii][jj];
    }
  }
}

// Split-K  Cpart[z] = A(M x K) B(N x K)^T over K-chunk z (128 wide). Tile 32x32, 2x2/thr.
__global__ __launch_bounds__(256) void k_gnt_splitk(const float* __restrict__ A, const float* __restrict__ B,
                                                    float* __restrict__ Cp, int M, int N, int K) {
  __shared__ float As[16][33];
  __shared__ float Bs[16][33];
  int tid = threadIdx.x, tx = tid % 16, ty = tid / 16;
  int row0 = blockIdx.y*32, col0 = blockIdx.x*32;
  int z = blockIdx.z;
  int kbeg = z*128, kend = kbeg + 128 < K ? kbeg + 128 : K;
  float acc[2][2] = {};
  for (int k0 = kbeg; k0 < kend; k0 += 16) {
    for (int i = tid; i < 512; i += 256) {
      int kk = i & 15, r = i >> 4;
      float v = 0.f;
      if (row0 + r < M && k0 + kk < K) v = A[(long)(row0+r)*K + k0 + kk];
      As[kk][r] = v;
    }
    for (int i = tid; i < 512; i += 256) {
      int kk = i & 15, c = i >> 4;
      float v = 0.f;
      if (col0 + c < N && k0 + kk < K) v = B[(long)(col0+c)*K + k0 + kk];
      Bs[kk][c] = v;
    }
    __syncthreads();
    for (int kk = 0; kk < 16; ++kk) {
      float a0 = As[kk][ty*2], a1 = As[kk][ty*2+1];
      float b0 = Bs[kk][tx*2], b1 = Bs[kk][tx*2+1];
      acc[0][0] += a0*b0; acc[0][1] += a0*b1;
      acc[1][0] += a1*b0; acc[1][1] += a1*b1;
    }
    __syncthreads();
  }
  long base = (long)z * M * N;
  for (int ii = 0; ii < 2; ++ii) {
    int r = row0 + ty*2 + ii;
    if (r >= M) continue;
    for (int jj = 0; jj < 2; ++jj) {
      int c = col0 + tx*2 + jj;
      if (c < N) Cp[base + (long)r*N + c] = acc[ii][jj];
    }
  }
}

// ---------------- subspace iteration pieces ----------------
__global__ void k_xinit(float* __restrict__ X, int n, unsigned seed) {
  int i = blockIdx.x * blockDim.x + threadIdx.x;
  if (i >= n) return;
  unsigned x = (unsigned)i * 2654435761u + seed;
  x ^= x >> 16; x *= 2246822519u; x ^= x >> 13; x *= 3266489917u; x ^= x >> 16;
  X[i] = (float)x * (1.0f/4294967296.0f) - 0.5f;
}

// Reduce split-K Gram partials (128x128) -> Cholesky with clamped pivots -> Lout + flags.
// ROUND-10 VERSION (block-parallel, 3 barriers/step) — empirically fastest of 3 variants.
__global__ __launch_bounds__(1024) void k_chol128(const float* __restrict__ Part, int nkz,
                                                  float* __restrict__ Lout) {
  __shared__ float G[128*129];
  __shared__ int flags[128];
  __shared__ float dminS;
  int tid = threadIdx.x;
  for (int i = tid; i < 16384; i += 1024) {
    float s = 0.f;
    for (int z = 0; z < nkz; ++z) s += Part[(long)z*16384 + i];
    G[(i >> 7)*129 + (i & 127)] = s;
  }
  __syncthreads();
  if (tid == 0) {
    float tr = 0.f;
    for (int i = 0; i < 128; ++i) tr += G[i*129+i];
    dminS = tr * (1e-12f/128.f) + 1e-30f;
  }
  __syncthreads();
  int ty = tid >> 5, tx = tid & 31;
  for (int k = 0; k < 128; ++k) {
    if (tid == 0) {
      float d = G[k*129+k];
      int bad = (d < dminS) ? 1 : 0;
      flags[k] = bad;
      G[k*129+k] = sqrtf(bad ? dminS : d);
    }
    __syncthreads();
    float lkk = G[k*129+k];
    int bad = flags[k];
    for (int i = k+1+tid; i < 128; i += 1024)
      G[i*129+k] = bad ? 0.f : (G[i*129+k] / lkk);
    __syncthreads();
    for (int i = k+1+ty; i < 128; i += 32)
      for (int j = k+1+tx; j <= i; j += 32)
        G[i*129+j] -= G[i*129+k] * G[j*129+k];
    __syncthreads();
  }
  for (int i = tid; i < 16384; i += 1024) Lout[i] = G[(i>>7)*129 + (i&127)];
  if (tid < 128) ((int*)Lout)[16384 + tid] = flags[tid];
}

// X (128 x Nm) <- L^{-1} X. One wave per column; L in LDS. Clamped rows re-seeded with noise.
__global__ __launch_bounds__(1024) void k_trisolve128(float* __restrict__ X, int Nm,
                                                      const float* __restrict__ Lin) {
  __shared__ float Ls[128*129];
  __shared__ int flags[128];
  int tid = threadIdx.x, wave = tid >> 6, lane = tid & 63;
  for (int i = tid; i < 16384; i += 1024) Ls[(i>>7)*129 + (i&127)] = Lin[i];
  if (tid < 128) flags[tid] = ((const int*)Lin)[16384 + tid];
  __syncthreads();
  int c = blockIdx.x*16 + wave;
  if (c >= Nm) return;
  float v0 = X[(long)lane*Nm + c];
  float v1 = X[(long)(lane+64)*Nm + c];
  for (int i = 0; i < 128; ++i) {
    float l0 = Ls[i*129 + lane];
    float l1 = Ls[i*129 + lane + 64];
    float partial = 0.f;
    if (lane < i) partial += l0 * v0;
    if (lane + 64 < i) partial += l1 * v1;
    for (int o = 32; o; o >>= 1) partial += __shfl_down(partial, o);
    float s = __shfl(partial, 0);
    float lii = Ls[i*129 + i];
    int bad = flags[i];
    unsigned h = (unsigned)(i*1315423911u) ^ (unsigned)(c*2654435761u);
    h ^= h >> 16; h *= 2246822519u; h ^= h >> 13;
    float noise = ((float)h * (1.0f/4294967296.0f) - 0.5f) * 1e-3f;
    if (i < 64) {
      if (lane == i)      v0 = bad ? noise : ((v0 - s) / lii);
    } else {
      if (lane == i - 64) v1 = bad ? noise : ((v1 - s) / lii);
    }
  }
  X[(long)lane*Nm + c] = v0;
  X[(long)(lane+64)*Nm + c] = v1;
}

// Jacobi 128x128 from split-K partials (fused reduce+symmetrize on load), early-exit,
// THRESHOLD-SKIP rounds, then fused post: |w|-select + C diag + Vsel + Vsrt.
__global__ __launch_bounds__(1024) void k_jacobi_post(const float* __restrict__ Part, int nkz,
                                                      float* __restrict__ Cmat, float* __restrict__ Vsel,
                                                      float* __restrict__ Vsrt, int maxsweeps) {
  const int n = KSUB;
  __shared__ float Bs[KSUB*KSUB];
  __shared__ float Vt[KSUB*KSUB];
  __shared__ float cS[64], sS[64];
  __shared__ int pS[64], qS[64];
  __shared__ float redA[16], redB[16];
  __shared__ int done;
  __shared__ int skipF;
  __shared__ float thrS;
  __shared__ int idxL[128];
  __shared__ float wsL[96];
  __shared__ float wsnL;
  int tid = threadIdx.x, wave = tid >> 6, lane = tid & 63;
  for (int i = tid; i < n*n; i += 1024) {
    int r = i >> 7, c = i & 127;
    float s1 = 0.f, s2 = 0.f;
    for (int z = 0; z < nkz; ++z) {
      s1 += Part[(long)z*16384 + i];
      s2 += Part[(long)z*16384 + c*128 + r];
    }
    Bs[i] = 0.5f*(s1 + s2);
    Vt[i] = (r == c) ? 1.f : 0.f;
  }
  if (tid == 0) done = 0;
  __syncthreads();
  {
    float dias = 0.f;
    for (int i = tid; i < n*n; i += 1024) {
      if ((i >> 7) == (i & 127)) { float v = Bs[i]; dias += v*v; }
    }
    for (int o = 32; o; o >>= 1) dias += __shfl_down(dias, o);
    if (lane == 0) redB[wave] = dias;
    __syncthreads();
    if (tid == 0) {
      float db = 0.f;
      for (int wv = 0; wv < 16; ++wv) db += redB[wv];
      thrS = 3e-6f * sqrtf(db / 128.f);
    }
    __syncthreads();
  }
  for (int sw = 0; sw < maxsweeps; ++sw) {
    for (int r = 0; r < n-1; ++r) {
      float myb = 0.f;
      if (tid < 64) {
        int k = tid, a, b;
        if (k == 0) { a = n-1; b = r % (n-1); }
        else { a = (r + k) % (n-1); b = (r - k + (n-1)) % (n-1); }
        int p = a < b ? a : b, q = a < b ? b : a;
        float bpp = Bs[p*n+p], bqq = Bs[q*n+q], bpq = Bs[p*n+q];
        float c = 1.f, s = 0.f;
        if (bpq != 0.f) {
          float tau = (bqq - bpp) / (2.f*bpq);
          float t = (tau >= 0.f ? 1.f : -1.f) / (fabsf(tau) + sqrtf(1.f + tau*tau));
          c = rsqrtf(1.f + t*t); s = t*c;
        }
        pS[k] = p; qS[k] = q; cS[k] = c; sS[k] = s;
        myb = fabsf(bpq);
      }
      if (tid < 64) {
        for (int o = 32; o; o >>= 1) { float ob = __shfl_down(myb, o); if (ob > myb) myb = ob; }
        if (tid == 0) skipF = (myb <= thrS) ? 1 : 0;
      }
      __syncthreads();
      if (!skipF) {
        for (int t = tid; t < 64*64; t += 1024) {
          int k1 = t >> 6, k2 = t & 63;
          int p1 = pS[k1], q1 = qS[k1]; float c1 = cS[k1], s1 = sS[k1];
          int p2 = pS[k2], q2 = qS[k2]; float c2 = cS[k2], s2 = sS[k2];
          float a = Bs[p1*n+p2], b = Bs[p1*n+q2], d = Bs[q1*n+p2], e = Bs[q1*n+q2];
          float a1 = c1*a - s1*d, b1 = c1*b - s1*e;
          float d1 = s1*a + c1*d, e1 = s1*b + c1*e;
          Bs[p1*n+p2] = c2*a1 - s2*b1; Bs[p1*n+q2] = s2*a1 + c2*b1;
          Bs[q1*n+p2] = c2*d1 - s2*e1; Bs[q1*n+q2] = s2*d1 + c2*e1;
        }
        for (int t = tid; t < 64*n; t += 1024) {
          int k = t >> 7, i = t & (n-1);
          int p = pS[k], q = qS[k]; float c = cS[k], s = sS[k];
          float vp = Vt[p*n+i], vq = Vt[q*n+i];
          Vt[p*n+i] = c*vp - s*vq; Vt[q*n+i] = s*vp + c*vq;
        }
      }
      __syncthreads();
    }
    float offs = 0.f, dias = 0.f;
    for (int i = tid; i < n*n; i += 1024) {
      float v = Bs[i];
      if ((i >> 7) == (i & 127)) dias += v*v; else offs += v*v;
    }
    for (int o = 32; o; o >>= 1) { offs += __shfl_down(offs, o); dias += __shfl_down(dias, o); }
    if (lane == 0) { redA[wave] = offs; redB[wave] = dias; }
    __syncthreads();
    if (tid == 0) {
      float oa = 0.f, db = 0.f;
      for (int wv = 0; wv < 16; ++wv) { oa += redA[wv]; db += redB[wv]; }
      done = (oa <= 1e-7f * db + 1e-30f) ? 1 : 0;
    }
    __syncthreads();
    if (done) break;
  }
  // ---- fused post: select top-|w| (wave 0), then write outputs ----
  if (tid < 64) {
    int l2 = tid;
    float v0 = Bs[l2*129], v1 = Bs[(l2+64)*129];
    float a0 = fabsf(v0), a1 = fabsf(v1);
    float ss = 0.f;
    for (int t = 0; t < n; ++t) {
      float b, bv; int bi;
      if (a0 >= a1) { b = a0; bi = l2; bv = v0; }
      else          { b = a1; bi = l2 + 64; bv = v1; }
      for (int o = 32; o; o >>= 1) {
        float ob = __shfl_down(b, o);
        int   oi = __shfl_down(bi, o);
        float ov = __shfl_down(bv, o);
        if (ob > b) { b = ob; bi = oi; bv = ov; }
      }
      bi = __shfl(bi, 0); bv = __shfl(bv, 0);
      if (l2 == 0) {
        idxL[t] = bi;
        if (t < 96) { wsL[t] = bv; ss += bv * bv; }
      }
      if (bi == l2) a0 = -1.f;
      if (bi == l2 + 64) a1 = -1.f;
    }
    if (l2 == 0) wsnL = sqrtf(ss);
  }
  __syncthreads();
  float invn = 1.f / wsnL;
  for (int i = tid; i < 96*96; i += 1024) {
    int r = i / 96, c = i % 96;
    Cmat[i] = (r == c) ? wsL[r] * invn : 0.f;
  }
  for (int i = tid; i < 128*96; i += 1024) {
    int q = i / 96, a = i % 96;
    Vsel[i] = Vt[idxL[a]*n + q];
  }
  for (int i = tid; i < 128*128; i += 1024) {
    int q = i >> 7, t = i & 127;
    Vsrt[i] = Vt[idxL[t]*n + q];
  }
}

// ---------------- observable stage ----------------
__global__ void k_buildK(const float* __restrict__ As, float* __restrict__ K6) {
  int i = blockIdx.x * blockDim.x + threadIdx.x;
  if (i >= 1024) return;
  int y = i & 3, v = (i>>2)&3, x = (i>>4)&3, u = (i>>6)&3, s = (i>>8)&1, p = (i>>9)&1;
  float acc = 0.f;
  for (int w = 0; w < 4; ++w)
    acc += As[((p*4+u)*4+x)*4+w] * As[((s*4+v)*4+y)*4+w];
  K6[i] = acc;
}

__global__ void k_Y1(const float* __restrict__ K6, const float* __restrict__ S, float* __restrict__ Y1) {
  int i = blockIdx.x * blockDim.x + threadIdx.x;
  if (i >= 1024) return;
  int f = i & 3, e = (i>>2)&3, b = (i>>4)&3, a = (i>>6)&3, s = (i>>8)&1, p = (i>>9)&1;
  float acc = 0.f;
  for (int u = 0; u < 4; ++u)
    for (int x = 0; x < 4; ++x)
      for (int v = 0; v < 4; ++v)
        for (int y = 0; y < 4; ++y)
          acc += K6[((((p*2+s)*4+u)*4+x)*4+v)*4+y]
               * S[(((x*4+b)*16 + (v*4+e))*16 + (y*4+f))*16 + (u*4+a)];
  Y1[i] = acc;
}

__global__ void k_W16(const float* __restrict__ K6, const float* __restrict__ Y1, float* __restrict__ W) {
  int i = threadIdx.x;
  if (i >= 16) return;
  int qr = i >> 2, ps = i & 3;
  float acc = 0.f;
  for (int j = 0; j < 256; ++j) acc += K6[qr*256 + j] * Y1[ps*256 + j];
  W[i] = acc;
}

__global__ void k_final(const float* __restrict__ W, const float* __restrict__ H,
                        const float* __restrict__ Ox, const float* __restrict__ Oy,
                        const float* __restrict__ Oz, float* __restrict__ out) {
  if (threadIdx.x != 0 || blockIdx.x != 0) return;
  float Z = 0.f;
  for (int q = 0; q < 2; ++q)
    for (int r = 0; r < 2; ++r) Z += W[((q*2+r)*2+q)*2+r];
  float ln = 0.f;
  for (int i = 0; i < 16; ++i) ln += H[i]*W[i];
  out[0] = ln / Z;
  const float* Os[3] = {Ox, Oy, Oz};
  for (int k = 0; k < 3; ++k) {
    float vA = 0.f, vB = 0.f;
    for (int q = 0; q < 2; ++q)
      for (int p = 0; p < 2; ++p)
        for (int r = 0; r < 2; ++r)
          vA += Os[k][q*2+p] * W[((q*2+r)*2+p)*2+r];
    for (int q = 0; q < 2; ++q)
      for (int r = 0; r < 2; ++r)
        for (int s = 0; s < 2; ++s)
          vB += Os[k][r*2+s] * W[((q*2+r)*2+q)*2+s];
    out[1+k] = 0.5f*(vA+vB)/Z;
  }
}

// ---------------- host ----------------
static inline unsigned nb256(long n) { long b = (n + 255) / 256; return (unsigned)(b < 1 ? 1 : b); }

extern "C" void kernel_launch(void* const* d_in, const int* in_sizes, int n_in,
                              void* d_out, int out_size, void* d_ws, size_t ws_size,
                              hipStream_t stream) {
  const float* A1  = (const float*)d_in[0];
  const float* Hin = (const float*)d_in[1];
  const float* Ox  = (const float*)d_in[2];
  const float* Oy  = (const float*)d_in[3];
  const float* Oz  = (const float*)d_in[4];

  const long SZ_BIG = 1536L*1536L;
  float* p0 = (float*)d_ws;
  float* Asym = p0; p0 += 128;
  float* Tb   = p0; p0 += 4096;
  float* Tvy  = p0; p0 += 4096;
  float* Mb   = p0; p0 += 65536;
  float* Ca   = p0; p0 += CHI*CHI;
  float* Cb   = p0; p0 += CHI*CHI;
  float* Ea   = p0; p0 += CHI*D2T*CHI;
  float* Eb   = p0; p0 += CHI*D2T*CHI;
  float* CE   = p0; p0 += CHI*D2T*CHI;
  float* E2   = p0; p0 += CHI*D2T*CHI;
  float* Pb   = p0; p0 += (CHI*D2T)*CHI;
  float* Xa   = p0; p0 += KSUB*(CHI*D2T);
  float* Xb   = p0; p0 += KSUB*(CHI*D2T);
  float* Vsrt = p0; p0 += KSUB*KSUB;
  float* Lb   = p0; p0 += 16384 + 128;
  float* Part = p0; p0 += 12*KSUB*KSUB;
  float* part = p0; p0 += NBRED;
  float* Vsel = p0; p0 += KSUB*CHI;
  float* K6   = p0; p0 += 1024;
  float* Y1   = p0; p0 += 1024;
  float* W16  = p0; p0 += 16;
  float* tb   = p0; p0 += CHI*D2T*CHI;
  float* ub   = p0; p0 += CHI*D2T*CHI;
  float* Sb   = p0; p0 += 65536;
  float* B1   = p0; p0 += SZ_BIG;
  float* B2   = p0; p0 += SZ_BIG;
  float* B3   = p0; p0 += SZ_BIG;
  if ((size_t)((char*)p0 - (char*)d_ws) > ws_size) return;

  auto normalize = [&](float* a, long n) {
    int nb = (int)((n + 255) / 256); if (nb > NBRED) nb = NBRED;
    k_sumsq<<<nb, 256, 0, stream>>>(a, n, part);
    k_scale_sumsq<<<nb256(n), 256, 0, stream>>>(a, n, part, nb);
  };
  auto gnn = [&](const float* A, const float* B, float* C, int M, int N, int K) {
    dim3 g((N+63)/64, (M+63)/64);
    k_gemm_nn<<<g, 256, 0, stream>>>(A, B, C, M, N, K);
  };
  auto gnnp = [&](const float* A, const float* B, float* C, int M, int N, int K,
                  int Ra, long sa, long sb, int Cbb, long sc, long sd) {
    dim3 g((N+63)/64, (M+63)/64);
    k_gemm_nn_p<<<g, 256, 0, stream>>>(A, B, C, M, N, K, Ra, sa, sb, Cbb, sc, sd);
  };
  auto gtn = [&](const float* A, const float* B, float* C, int M, int N, int K, int sub = 0) {
    dim3 g((N+63)/64, (M+63)/64);
    k_gemm_tn<<<g, 256, 0, stream>>>(A, B, C, M, N, K, sub);
  };
  auto gtnp = [&](const float* A, const float* B, float* C, int M, int N, int K,
                  int Ra, long sa, long sb, int Cbb, long sc, long sd) {
    dim3 g((N+63)/64, (M+63)/64);
    k_gemm_tn_p<<<g, 256, 0, stream>>>(A, B, C, M, N, K, Ra, sa, sb, Cbb, sc, sd);
  };
  // Full-basis CholQR: `passes` x (split-K Gram -> chol128 -> trisolve).
  auto ORTH = [&](float* Y, int Nm, int passes) {
    int Sk = Nm >> 7;
    for (int pass = 0; pass < passes; ++pass) {
      dim3 g(4, 4, Sk);
      k_gnt_splitk<<<g, 256, 0, stream>>>(Y, Y, Part, KSUB, KSUB, Nm);
      k_chol128<<<1, 1024, 0, stream>>>(Part, Sk, Lb);
      k_trisolve128<<<(Nm+15)/16, 1024, 0, stream>>>(Y, Nm, Lb);
    }
  };

  // ---- Stage A ----
  k_symA<<<1, 128, 0, stream>>>(A1, Asym);
  k_buildT<<<16, 256, 0, stream>>>(Asym, Tb);
  normalize(Tb, 4096);
  // Tvy[w][(v,y)] = T[v,y,w]  (for rank-16 factorized M-contractions; T fully symmetric
  // in its 3 fused legs, so T[u,x,w]=T[x,u,w] = Tb's natural 256x16 layout)
  k_perm4<<<16, 256, 0, stream>>>(Tb, Tvy, 16,16,16,1, 1L,256L,16L,0L);
  k_buildM<<<256, 256, 0, stream>>>(Tb, Mb);
  normalize(Mb, 65536);
  k_initC<<<1, 256, 0, stream>>>(Mb, Ca);
  k_sym2d<<<1, 256, 0, stream>>>(Ca, 16);
  normalize(Ca, 256);
  k_initE<<<16, 256, 0, stream>>>(Mb, Ea);
  k_symE_sumsq<<<16, 256, 0, stream>>>(Ea, 16, part);
  k_scale_sumsq<<<nb256(4096), 256, 0, stream>>>(Ea, 4096, part, 16);

  // ---- CTMRG iterations ----
  // NOTE: m is now built via the rank-16 factorization M = T (x) T (through w), which
  // drops the old 1/||M|| normalization. Pure global scale: C is eigenvalue-normalized,
  // E is normalized, all solver thresholds are relative, observables are ratios.
  const int nqs[NITER] = {8, 6, 2, 1, 1, 1, 1, 1, 1, 1, 1, 2};
  float* Ccur = Ca; float* Calt = Cb;
  float* Ecur = Ea; float* Ealt = Eb;
  float* baseB[2] = {Xa, Xb};
  int cur = 0;
  int chic = 16;
  for (int it = 0; it < NITER; ++it) {
    int Nm = chic * D2T;
    int chin = CHI;
    int nq = nqs[it];
    int coldInit = (it <= 1) ? 1 : 0;
    int doRotate = (it >= 1 && it < NITER-1) ? 1 : 0;
    int finalPasses = (it <= 1 || it == NITER-1) ? 2 : 1;
    // ---- Rho build (rank-16 factorized; perms fused into GEMM epilogues) ----
    gnn(Ccur, Ecur, CE, chic, D2T*chic, chic);                                 // CE[a,(x,i)]
    k_perm4<<<nb256((long)chic*chic*16), 256, 0, stream>>>(Ecur, E2,
        chic, chic, 16, 1, 1L, (long)16*chic, (long)chic, 0L);                 // E2[a,(j,u)]
    gtnp(CE, E2, B2, 16*chic, 16*chic, chic,
         chic, (long)chic*256, 16L, 16, 1L, 256L);                             // D1p[(i,j),(x,u)] -> B2
    gnn(B2, Tb, B3, chic*chic, 16, 256);                                       // R[ij,w] = D1p . T
    gnnp(B3, Tvy, B1, chic*chic, 256, 16,
         chic, 16L, (long)256*chic, 16, 1L, (long)16*chic);                    // m[(i,v),(j,y)] -> B1
    float* msym = B1;

    // ---- subspace eigensolve ----
    float* Xc = baseB[cur]; float* Yc = baseB[1-cur];
    if (coldInit)
      k_xinit<<<nb256((long)KSUB*Nm), 256, 0, stream>>>(Xc, KSUB*Nm, 0x9E3779B9u);
    int orthEvery = (it <= 1) ? 4 : 2;
    int since = 0;
    for (int t = 0; t < nq; ++t) {
      gnn(Xc, msym, Yc, KSUB, Nm, Nm);      // Y = X m
      { float* tm = Xc; Xc = Yc; Yc = tm; }
      if (++since >= orthEvery || t == nq-1) {
        ORTH(Xc, Nm, (t == nq-1) ? finalPasses : 1);
        since = 0;
      }
    }
    gnn(Xc, msym, Yc, KSUB, Nm, Nm);        // Y2 = X m
    {
      int Sk = Nm >> 7;
      dim3 g(4, 4, Sk);
      k_gnt_splitk<<<g, 256, 0, stream>>>(Yc, Xc, Part, KSUB, KSUB, Nm);   // Bsm partials
      k_jacobi_post<<<1, 1024, 0, stream>>>(Part, Sk, Calt, Vsel, Vsrt, JSWMAX);
    }
    gtn(Xc, Vsel, Pb, Nm, chin, KSUB);      // P (Nm x chin) = Ritz vectors
    if (doRotate) {
      gtn(Vsrt, Xc, Yc, KSUB, Nm, KSUB);    // Xnew = Vsrt^T Xc (orthonormal rotation)
      float* tm = Xc; Xc = Yc; Yc = tm;
    }
    cur = (Xc == Xa) ? 0 : 1;

    // ---- E update (rank-16 factorized; perms fused into GEMM epilogues) ----
    gtnp(Pb, Ecur, B1, D2T*chin, D2T*chic, chic,
         chin, (long)chic*256, 16L, chic, 256L, 1L);                           // T1p[(a,j),(u,x)] -> B1
    gnn(B1, Tb, B3, chin*chic, 16, 256);                                       // R2[aj,w] = T1p . T
    gnnp(B3, Tvy, B2, chin*chic, 256, 16,
         chic, 16L, (long)256*chic, 16, (long)16*chic, 1L);                    // T2p[(a,y),(j,v)] -> B2
    gnn(B2, Pb, Ealt, chin*D2T, chin, chic*D2T);                               // Enew[(a,y),b]
    k_symE_sumsq<<<NBRED, 256, 0, stream>>>(Ealt, chin, part);
    k_scale_sumsq<<<nb256((long)chin*16*chin), 256, 0, stream>>>(Ealt, (long)chin*16*chin, part, NBRED);
    { float* t1 = Ccur; Ccur = Calt; Calt = t1; }
    { float* t1 = Ecur; Ecur = Ealt; Ealt = t1; }
    chic = chin;
  }

  // ---- Environment closure: S_env and observables ----
  gnn(Ccur, Ecur, tb, CHI, D2T*CHI, CHI);                   // t[a,(x,c)]
  gnn(tb, Ccur, ub, CHI*D2T, CHI, CHI);                     // up[(a,x),d]
  gnn(ub, Ecur, B1, CHI*D2T, D2T*CHI, CHI);                 // T1env[(a,x),(v,e)]
  k_perm4<<<nb256(SZ_BIG), 256, 0, stream>>>(B1, B2,
      16, 16, CHI, CHI, 1536L, 96L, 24576L, 1L);            // A'[(X,V),(a,e)]
  k_perm4<<<nb256(SZ_BIG), 256, 0, stream>>>(B1, B3,
      CHI, CHI, 16, 16, 1L, 24576L, 1536L, 96L);            // B'[(a,e),(Y,U)]
  gnn(B2, B3, Sb, 256, 256, CHI*CHI);                       // S[X,V,Y,U]
  k_buildK<<<4, 256, 0, stream>>>(Asym, K6);
  k_Y1<<<4, 256, 0, stream>>>(K6, Sb, Y1);
  k_W16<<<1, 16, 0, stream>>>(K6, Y1, W16);
  k_final<<<1, 1, 0, stream>>>(W16, Hin, Ox, Oy, Oz, (float*)d_out);
}

// Round 17
// 19978.546 us; speedup vs baseline: 1.2366x; 1.2366x over previous
//
#include <hip/hip_runtime.h>
#include <math.h>

#define D2T   16
#define CHI   96
#define NITER 12
#define KSUB  128
#define JSWMAX 12
#define NBRED 128

// ---------------- tiny builders ----------------
__global__ void k_symA(const float* __restrict__ A1, float* __restrict__ As) {
  int i = blockIdx.x * blockDim.x + threadIdx.x;
  if (i >= 128) return;
  int w = i % 4, x = (i / 4) % 4, u = (i / 16) % 4, p = i / 64;
#define AT(pp,aa,bb,cc) A1[(((pp)*4+(aa))*4+(bb))*4+(cc)]
  As[i] = AT(p,u,x,w) + AT(p,u,w,x) + AT(p,x,w,u) + AT(p,w,x,u) + AT(p,w,u,x) + AT(p,x,u,w);
#undef AT
}

__global__ void k_buildT(const float* __restrict__ As, float* __restrict__ T) {
  int i = blockIdx.x * blockDim.x + threadIdx.x;
  if (i >= 4096) return;
  int Wf = i % 16, Xf = (i / 16) % 16, Uf = i / 256;
  int u = Uf >> 2, a = Uf & 3, x = Xf >> 2, b = Xf & 3, w = Wf >> 2, c = Wf & 3;
  float s = 0.f;
  for (int p = 0; p < 2; ++p)
    s += As[((p*4+u)*4+x)*4+w] * As[((p*4+a)*4+b)*4+c];
  T[i] = s;
}

__global__ void k_buildM(const float* __restrict__ T, float* __restrict__ M) {
  int i = blockIdx.x * blockDim.x + threadIdx.x;
  if (i >= 65536) return;
  int y = i % 16, x = (i / 16) % 16, v = (i / 256) % 16, u = i / 4096;
  const float* Tu = T + (u*16 + x)*16;
  const float* Tv = T + (v*16 + y)*16;
  float s = 0.f;
  for (int w = 0; w < 16; ++w) s += Tu[w]*Tv[w];
  M[i] = s;
}

__global__ void k_initC(const float* __restrict__ M, float* __restrict__ C) {
  int i = blockIdx.x * blockDim.x + threadIdx.x;
  if (i >= 256) return;
  int v = i / 16, y = i % 16;
  float s = 0.f;
  for (int u = 0; u < 16; ++u)
    for (int x = 0; x < 16; ++x)
      s += M[((u*16+v)*16+x)*16+y];
  C[v*16+y] = s;
}

__global__ void k_initE(const float* __restrict__ M, float* __restrict__ E) {
  int i = blockIdx.x * blockDim.x + threadIdx.x;
  if (i >= 4096) return;
  int v = i % 16, y = (i / 16) % 16, u = i / 256;
  float s = 0.f;
  for (int x = 0; x < 16; ++x) s += M[((u*16+v)*16+x)*16+y];
  E[(u*16+y)*16+v] = s;   // E[u][y][v], chic=16
}

// ---------------- generic helpers ----------------
__global__ void k_perm4(const float* __restrict__ src, float* __restrict__ dst,
                        int d0, int d1, int d2, int d3,
                        long s0, long s1, long s2, long s3) {
  long n = (long)d0 * d1 * d2 * d3;
  for (long i = blockIdx.x * (long)blockDim.x + threadIdx.x; i < n;
       i += (long)gridDim.x * blockDim.x) {
    int i3 = (int)(i % d3); long t = i / d3;
    int i2 = (int)(t % d2); t /= d2;
    int i1 = (int)(t % d1); int i0 = (int)(t / d1);
    dst[i] = src[i0*s0 + i1*s1 + i2*s2 + i3*s3];
  }
}

__global__ void k_sym2d(float* __restrict__ A, int n) {
  long nn = (long)n * n;
  for (long i = blockIdx.x * (long)blockDim.x + threadIdx.x; i < nn;
       i += (long)gridDim.x * blockDim.x) {
    int r = (int)(i / n), c = (int)(i % n);
    if (r <= c) {
      float v = 0.5f * (A[(long)r*n + c] + A[(long)c*n + r]);
      A[(long)r*n + c] = v; A[(long)c*n + r] = v;
    }
  }
}

// fused: symmetrize E (a<=b pairs) AND accumulate ||E||^2 partials (off-diag counted twice)
__global__ void k_symE_sumsq(float* __restrict__ E, int chi, float* __restrict__ partial) {
  __shared__ float red[256];
  long n = (long)chi * 16 * chi;
  float s = 0.f;
  for (long i = blockIdx.x * (long)blockDim.x + threadIdx.x; i < n;
       i += (long)gridDim.x * blockDim.x) {
    int b = (int)(i % chi); long t = i / chi;
    int y = (int)(t % 16); int a = (int)(t / 16);
    if (a <= b) {
      long ia = ((long)a*16 + y)*chi + b, ib = ((long)b*16 + y)*chi + a;
      float v = 0.5f * (E[ia] + E[ib]);
      E[ia] = v; E[ib] = v;
      s += (a == b) ? v*v : 2.f*v*v;
    }
  }
  red[threadIdx.x] = s; __syncthreads();
  for (int o = 128; o; o >>= 1) { if ((int)threadIdx.x < o) red[threadIdx.x] += red[threadIdx.x + o]; __syncthreads(); }
  if (threadIdx.x == 0) partial[blockIdx.x] = red[0];
}

__global__ void k_sumsq(const float* __restrict__ a, long n, float* __restrict__ partial) {
  __shared__ float red[256];
  float s = 0.f;
  for (long i = blockIdx.x * 256L + threadIdx.x; i < n; i += (long)gridDim.x * 256L) {
    float v = a[i]; s += v*v;
  }
  red[threadIdx.x] = s; __syncthreads();
  for (int o = 128; o; o >>= 1) { if ((int)threadIdx.x < o) red[threadIdx.x] += red[threadIdx.x + o]; __syncthreads(); }
  if (threadIdx.x == 0) partial[blockIdx.x] = red[0];
}

__global__ void k_scale_sumsq(float* __restrict__ a, long n,
                              const float* __restrict__ partial, int nb) {
  __shared__ float red[256];
  float s = 0.f;
  for (int i = threadIdx.x; i < nb; i += 256) s += partial[i];
  red[threadIdx.x] = s; __syncthreads();
  for (int o = 128; o; o >>= 1) { if ((int)threadIdx.x < o) red[threadIdx.x] += red[threadIdx.x + o]; __syncthreads(); }
  float f = rsqrtf(red[0]);
  for (long i = blockIdx.x * (long)blockDim.x + threadIdx.x; i < n;
       i += (long)gridDim.x * blockDim.x) a[i] *= f;
}

__global__ void k_reduceK(const float* __restrict__ in, float* __restrict__ out, long mn, int S) {
  for (long i = blockIdx.x * (long)blockDim.x + threadIdx.x; i < mn;
       i += (long)gridDim.x * blockDim.x) {
    float s = 0.f;
    for (int z = 0; z < S; ++z) s += in[(long)z*mn + i];
    out[i] = s;
  }
}

// ---------------- GEMMs (fp32, 64x64 tile, 256 thr, 4x4/thr) ----------------
__global__ __launch_bounds__(256) void k_gemm_nn(const float* __restrict__ A, const float* __restrict__ B,
                                                 float* __restrict__ C, int M, int N, int K) {
  __shared__ float As[16][68];
  __shared__ float Bs[16][68];
  int tid = threadIdx.x, tx = tid % 16, ty = tid / 16;
  int row0 = blockIdx.y*64, col0 = blockIdx.x*64;
  float acc[4][4] = {};
  for (int k0 = 0; k0 < K; k0 += 16) {
    for (int i = tid; i < 16*64; i += 256) {
      int c = i % 16, r = i / 16;
      float v = 0.f;
      if (row0 + r < M && k0 + c < K) v = A[(long)(row0+r)*K + k0 + c];
      As[c][r] = v;
    }
    for (int i = tid; i < 16*64; i += 256) {
      int c = i % 64, r = i / 64;
      float v = 0.f;
      if (k0 + r < K && col0 + c < N) v = B[(long)(k0+r)*N + col0 + c];
      Bs[r][c] = v;
    }
    __syncthreads();
    for (int kk = 0; kk < 16; ++kk) {
      float av[4], bv[4];
#pragma unroll
      for (int ii = 0; ii < 4; ++ii) av[ii] = As[kk][ty*4+ii];
#pragma unroll
      for (int jj = 0; jj < 4; ++jj) bv[jj] = Bs[kk][tx*4+jj];
#pragma unroll
      for (int ii = 0; ii < 4; ++ii)
#pragma unroll
        for (int jj = 0; jj < 4; ++jj) acc[ii][jj] += av[ii]*bv[jj];
    }
    __syncthreads();
  }
  for (int ii = 0; ii < 4; ++ii) {
    int r = row0 + ty*4 + ii;
    if (r >= M) continue;
    for (int jj = 0; jj < 4; ++jj) {
      int c = col0 + tx*4 + jj;
      if (c < N) C[(long)r*N + c] = acc[ii][jj];
    }
  }
}

// nn GEMM with permuted output: dst = (r%Ra)*sa + (r/Ra)*sb + (c%Cb)*sc + (c/Cb)*sd
__global__ __launch_bounds__(256) void k_gemm_nn_p(const float* __restrict__ A, const float* __restrict__ B,
                                                   float* __restrict__ C, int M, int N, int K,
                                                   int Ra, long sa, long sb, int Cb, long sc, long sd) {
  __shared__ float As[16][68];
  __shared__ float Bs[16][68];
  int tid = threadIdx.x, tx = tid % 16, ty = tid / 16;
  int row0 = blockIdx.y*64, col0 = blockIdx.x*64;
  float acc[4][4] = {};
  for (int k0 = 0; k0 < K; k0 += 16) {
    for (int i = tid; i < 16*64; i += 256) {
      int c = i % 16, r = i / 16;
      float v = 0.f;
      if (row0 + r < M && k0 + c < K) v = A[(long)(row0+r)*K + k0 + c];
      As[c][r] = v;
    }
    for (int i = tid; i < 16*64; i += 256) {
      int c = i % 64, r = i / 64;
      float v = 0.f;
      if (k0 + r < K && col0 + c < N) v = B[(long)(k0+r)*N + col0 + c];
      Bs[r][c] = v;
    }
    __syncthreads();
    for (int kk = 0; kk < 16; ++kk) {
      float av[4], bv[4];
#pragma unroll
      for (int ii = 0; ii < 4; ++ii) av[ii] = As[kk][ty*4+ii];
#pragma unroll
      for (int jj = 0; jj < 4; ++jj) bv[jj] = Bs[kk][tx*4+jj];
#pragma unroll
      for (int ii = 0; ii < 4; ++ii)
#pragma unroll
        for (int jj = 0; jj < 4; ++jj) acc[ii][jj] += av[ii]*bv[jj];
    }
    __syncthreads();
  }
  for (int ii = 0; ii < 4; ++ii) {
    int r = row0 + ty*4 + ii;
    if (r >= M) continue;
    long ro = (long)(r % Ra)*sa + (long)(r / Ra)*sb;
    for (int jj = 0; jj < 4; ++jj) {
      int c = col0 + tx*4 + jj;
      if (c < N) C[ro + (long)(c % Cb)*sc + (long)(c / Cb)*sd] = acc[ii][jj];
    }
  }
}

// C = A^T B (sub=0) or C -= A^T B (sub=1); A is (K x M) row-major, B is (K x N) row-major
__global__ __launch_bounds__(256) void k_gemm_tn(const float* __restrict__ A, const float* __restrict__ B,
                                                 float* __restrict__ C, int M, int N, int K, int sub) {
  __shared__ float As[16][68];
  __shared__ float Bs[16][68];
  int tid = threadIdx.x, tx = tid % 16, ty = tid / 16;
  int row0 = blockIdx.y*64, col0 = blockIdx.x*64;
  float acc[4][4] = {};
  for (int k0 = 0; k0 < K; k0 += 16) {
    for (int i = tid; i < 16*64; i += 256) {
      int r = i % 64, kk = i / 64;
      float v = 0.f;
      if (k0 + kk < K && row0 + r < M) v = A[(long)(k0+kk)*M + row0 + r];
      As[kk][r] = v;
    }
    for (int i = tid; i < 16*64; i += 256) {
      int c = i % 64, kk = i / 64;
      float v = 0.f;
      if (k0 + kk < K && col0 + c < N) v = B[(long)(k0+kk)*N + col0 + c];
      Bs[kk][c] = v;
    }
    __syncthreads();
    for (int kk = 0; kk < 16; ++kk) {
      float av[4], bv[4];
#pragma unroll
      for (int ii = 0; ii < 4; ++ii) av[ii] = As[kk][ty*4+ii];
#pragma unroll
      for (int jj = 0; jj < 4; ++jj) bv[jj] = Bs[kk][tx*4+jj];
#pragma unroll
      for (int ii = 0; ii < 4; ++ii)
#pragma unroll
        for (int jj = 0; jj < 4; ++jj) acc[ii][jj] += av[ii]*bv[jj];
    }
    __syncthreads();
  }
  for (int ii = 0; ii < 4; ++ii) {
    int r = row0 + ty*4 + ii;
    if (r >= M) continue;
    for (int jj = 0; jj < 4; ++jj) {
      int c = col0 + tx*4 + jj;
      if (c < N) {
        if (sub) C[(long)r*N + c] -= acc[ii][jj];
        else     C[(long)r*N + c]  = acc[ii][jj];
      }
    }
  }
}

// tn GEMM with permuted output (same dst mapping as nn_p)
__global__ __launch_bounds__(256) void k_gemm_tn_p(const float* __restrict__ A, const float* __restrict__ B,
                                                   float* __restrict__ C, int M, int N, int K,
                                                   int Ra, long sa, long sb, int Cb, long sc, long sd) {
  __shared__ float As[16][68];
  __shared__ float Bs[16][68];
  int tid = threadIdx.x, tx = tid % 16, ty = tid / 16;
  int row0 = blockIdx.y*64, col0 = blockIdx.x*64;
  float acc[4][4] = {};
  for (int k0 = 0; k0 < K; k0 += 16) {
    for (int i = tid; i < 16*64; i += 256) {
      int r = i % 64, kk = i / 64;
      float v = 0.f;
      if (k0 + kk < K && row0 + r < M) v = A[(long)(k0+kk)*M + row0 + r];
      As[kk][r] = v;
    }
    for (int i = tid; i < 16*64; i += 256) {
      int c = i % 64, kk = i / 64;
      float v = 0.f;
      if (k0 + kk < K && col0 + c < N) v = B[(long)(k0+kk)*N + col0 + c];
      Bs[kk][c] = v;
    }
    __syncthreads();
    for (int kk = 0; kk < 16; ++kk) {
      float av[4], bv[4];
#pragma unroll
      for (int ii = 0; ii < 4; ++ii) av[ii] = As[kk][ty*4+ii];
#pragma unroll
      for (int jj = 0; jj < 4; ++jj) bv[jj] = Bs[kk][tx*4+jj];
#pragma unroll
      for (int ii = 0; ii < 4; ++ii)
#pragma unroll
        for (int jj = 0; jj < 4; ++jj) acc[ii][jj] += av[ii]*bv[jj];
    }
    __syncthreads();
  }
  for (int ii = 0; ii < 4; ++ii) {
    int r = row0 + ty*4 + ii;
    if (r >= M) continue;
    long ro = (long)(r % Ra)*sa + (long)(r / Ra)*sb;
    for (int jj = 0; jj < 4; ++jj) {
      int c = col0 + tx*4 + jj;
      if (c < N) C[ro + (long)(c % Cb)*sc + (long)(c / Cb)*sd] = acc[ii][jj];
    }
  }
}

// Split-K  Cpart[z] = A(M x K) B(N x K)^T over K-chunk z (128 wide). Tile 32x32, 2x2/thr.
__global__ __launch_bounds__(256) void k_gnt_splitk(const float* __restrict__ A, const float* __restrict__ B,
                                                    float* __restrict__ Cp, int M, int N, int K) {
  __shared__ float As[16][33];
  __shared__ float Bs[16][33];
  int tid = threadIdx.x, tx = tid % 16, ty = tid / 16;
  int row0 = blockIdx.y*32, col0 = blockIdx.x*32;
  int z = blockIdx.z;
  int kbeg = z*128, kend = kbeg + 128 < K ? kbeg + 128 : K;
  float acc[2][2] = {};
  for (int k0 = kbeg; k0 < kend; k0 += 16) {
    for (int i = tid; i < 512; i += 256) {
      int kk = i & 15, r = i >> 4;
      float v = 0.f;
      if (row0 + r < M && k0 + kk < K) v = A[(long)(row0+r)*K + k0 + kk];
      As[kk][r] = v;
    }
    for (int i = tid; i < 512; i += 256) {
      int kk = i & 15, c = i >> 4;
      float v = 0.f;
      if (col0 + c < N && k0 + kk < K) v = B[(long)(col0+c)*K + k0 + kk];
      Bs[kk][c] = v;
    }
    __syncthreads();
    for (int kk = 0; kk < 16; ++kk) {
      float a0 = As[kk][ty*2], a1 = As[kk][ty*2+1];
      float b0 = Bs[kk][tx*2], b1 = Bs[kk][tx*2+1];
      acc[0][0] += a0*b0; acc[0][1] += a0*b1;
      acc[1][0] += a1*b0; acc[1][1] += a1*b1;
    }
    __syncthreads();
  }
  long base = (long)z * M * N;
  for (int ii = 0; ii < 2; ++ii) {
    int r = row0 + ty*2 + ii;
    if (r >= M) continue;
    for (int jj = 0; jj < 2; ++jj) {
      int c = col0 + tx*2 + jj;
      if (c < N) Cp[base + (long)r*N + c] = acc[ii][jj];
    }
  }
}

// ---------------- subspace iteration pieces ----------------
__global__ void k_xinit(float* __restrict__ X, int n, unsigned seed) {
  int i = blockIdx.x * blockDim.x + threadIdx.x;
  if (i >= n) return;
  unsigned x = (unsigned)i * 2654435761u + seed;
  x ^= x >> 16; x *= 2246822519u; x ^= x >> 13; x *= 3266489917u; x ^= x >> 16;
  X[i] = (float)x * (1.0f/4294967296.0f) - 0.5f;
}

// Reduce split-K Gram partials (128x128) -> Cholesky with clamped pivots -> Lout + flags.
// ROUND-10 VERSION (block-parallel, 3 barriers/step) — empirically fastest of 3 variants.
__global__ __launch_bounds__(1024) void k_chol128(const float* __restrict__ Part, int nkz,
                                                  float* __restrict__ Lout) {
  __shared__ float G[128*129];
  __shared__ int flags[128];
  __shared__ float dminS;
  int tid = threadIdx.x;
  for (int i = tid; i < 16384; i += 1024) {
    float s = 0.f;
    for (int z = 0; z < nkz; ++z) s += Part[(long)z*16384 + i];
    G[(i >> 7)*129 + (i & 127)] = s;
  }
  __syncthreads();
  if (tid == 0) {
    float tr = 0.f;
    for (int i = 0; i < 128; ++i) tr += G[i*129+i];
    dminS = tr * (1e-12f/128.f) + 1e-30f;
  }
  __syncthreads();
  int ty = tid >> 5, tx = tid & 31;
  for (int k = 0; k < 128; ++k) {
    if (tid == 0) {
      float d = G[k*129+k];
      int bad = (d < dminS) ? 1 : 0;
      flags[k] = bad;
      G[k*129+k] = sqrtf(bad ? dminS : d);
    }
    __syncthreads();
    float lkk = G[k*129+k];
    int bad = flags[k];
    for (int i = k+1+tid; i < 128; i += 1024)
      G[i*129+k] = bad ? 0.f : (G[i*129+k] / lkk);
    __syncthreads();
    for (int i = k+1+ty; i < 128; i += 32)
      for (int j = k+1+tx; j <= i; j += 32)
        G[i*129+j] -= G[i*129+k] * G[j*129+k];
    __syncthreads();
  }
  for (int i = tid; i < 16384; i += 1024) Lout[i] = G[(i>>7)*129 + (i&127)];
  if (tid < 128) ((int*)Lout)[16384 + tid] = flags[tid];
}

// X (128 x Nm) <- L^{-1} X. One wave per column; L in LDS. Clamped rows re-seeded with noise.
__global__ __launch_bounds__(1024) void k_trisolve128(float* __restrict__ X, int Nm,
                                                      const float* __restrict__ Lin) {
  __shared__ float Ls[128*129];
  __shared__ int flags[128];
  int tid = threadIdx.x, wave = tid >> 6, lane = tid & 63;
  for (int i = tid; i < 16384; i += 1024) Ls[(i>>7)*129 + (i&127)] = Lin[i];
  if (tid < 128) flags[tid] = ((const int*)Lin)[16384 + tid];
  __syncthreads();
  int c = blockIdx.x*16 + wave;
  if (c >= Nm) return;
  float v0 = X[(long)lane*Nm + c];
  float v1 = X[(long)(lane+64)*Nm + c];
  for (int i = 0; i < 128; ++i) {
    float l0 = Ls[i*129 + lane];
    float l1 = Ls[i*129 + lane + 64];
    float partial = 0.f;
    if (lane < i) partial += l0 * v0;
    if (lane + 64 < i) partial += l1 * v1;
    for (int o = 32; o; o >>= 1) partial += __shfl_down(partial, o);
    float s = __shfl(partial, 0);
    float lii = Ls[i*129 + i];
    int bad = flags[i];
    unsigned h = (unsigned)(i*1315423911u) ^ (unsigned)(c*2654435761u);
    h ^= h >> 16; h *= 2246822519u; h ^= h >> 13;
    float noise = ((float)h * (1.0f/4294967296.0f) - 0.5f) * 1e-3f;
    if (i < 64) {
      if (lane == i)      v0 = bad ? noise : ((v0 - s) / lii);
    } else {
      if (lane == i - 64) v1 = bad ? noise : ((v1 - s) / lii);
    }
  }
  X[(long)lane*Nm + c] = v0;
  X[(long)(lane+64)*Nm + c] = v1;
}

// Jacobi 128x128 from split-K partials (fused reduce+symmetrize on load), early-exit,
// THRESHOLD-SKIP rounds, then fused post: |w|-select + C diag + Vsel + Vsrt.
__global__ __launch_bounds__(1024) void k_jacobi_post(const float* __restrict__ Part, int nkz,
                                                      float* __restrict__ Cmat, float* __restrict__ Vsel,
                                                      float* __restrict__ Vsrt, int maxsweeps) {
  const int n = KSUB;
  __shared__ float Bs[KSUB*KSUB];
  __shared__ float Vt[KSUB*KSUB];
  __shared__ float cS[64], sS[64];
  __shared__ int pS[64], qS[64];
  __shared__ float redA[16], redB[16];
  __shared__ int done;
  __shared__ int skipF;
  __shared__ float thrS;
  __shared__ int idxL[128];
  __shared__ float wsL[96];
  __shared__ float wsnL;
  int tid = threadIdx.x, wave = tid >> 6, lane = tid & 63;
  for (int i = tid; i < n*n; i += 1024) {
    int r = i >> 7, c = i & 127;
    float s1 = 0.f, s2 = 0.f;
    for (int z = 0; z < nkz; ++z) {
      s1 += Part[(long)z*16384 + i];
      s2 += Part[(long)z*16384 + c*128 + r];
    }
    Bs[i] = 0.5f*(s1 + s2);
    Vt[i] = (r == c) ? 1.f : 0.f;
  }
  if (tid == 0) done = 0;
  __syncthreads();
  {
    float dias = 0.f;
    for (int i = tid; i < n*n; i += 1024) {
      if ((i >> 7) == (i & 127)) { float v = Bs[i]; dias += v*v; }
    }
    for (int o = 32; o; o >>= 1) dias += __shfl_down(dias, o);
    if (lane == 0) redB[wave] = dias;
    __syncthreads();
    if (tid == 0) {
      float db = 0.f;
      for (int wv = 0; wv < 16; ++wv) db += redB[wv];
      thrS = 3e-6f * sqrtf(db / 128.f);
    }
    __syncthreads();
  }
  for (int sw = 0; sw < maxsweeps; ++sw) {
    for (int r = 0; r < n-1; ++r) {
      float myb = 0.f;
      if (tid < 64) {
        int k = tid, a, b;
        if (k == 0) { a = n-1; b = r % (n-1); }
        else { a = (r + k) % (n-1); b = (r - k + (n-1)) % (n-1); }
        int p = a < b ? a : b, q = a < b ? b : a;
        float bpp = Bs[p*n+p], bqq = Bs[q*n+q], bpq = Bs[p*n+q];
        float c = 1.f, s = 0.f;
        if (bpq != 0.f) {
          float tau = (bqq - bpp) / (2.f*bpq);
          float t = (tau >= 0.f ? 1.f : -1.f) / (fabsf(tau) + sqrtf(1.f + tau*tau));
          c = rsqrtf(1.f + t*t); s = t*c;
        }
        pS[k] = p; qS[k] = q; cS[k] = c; sS[k] = s;
        myb = fabsf(bpq);
      }
      if (tid < 64) {
        for (int o = 32; o; o >>= 1) { float ob = __shfl_down(myb, o); if (ob > myb) myb = ob; }
        if (tid == 0) skipF = (myb <= thrS) ? 1 : 0;
      }
      __syncthreads();
      if (!skipF) {
        for (int t = tid; t < 64*64; t += 1024) {
          int k1 = t >> 6, k2 = t & 63;
          int p1 = pS[k1], q1 = qS[k1]; float c1 = cS[k1], s1 = sS[k1];
          int p2 = pS[k2], q2 = qS[k2]; float c2 = cS[k2], s2 = sS[k2];
          float a = Bs[p1*n+p2], b = Bs[p1*n+q2], d = Bs[q1*n+p2], e = Bs[q1*n+q2];
          float a1 = c1*a - s1*d, b1 = c1*b - s1*e;
          float d1 = s1*a + c1*d, e1 = s1*b + c1*e;
          Bs[p1*n+p2] = c2*a1 - s2*b1; Bs[p1*n+q2] = s2*a1 + c2*b1;
          Bs[q1*n+p2] = c2*d1 - s2*e1; Bs[q1*n+q2] = s2*d1 + c2*e1;
        }
        for (int t = tid; t < 64*n; t += 1024) {
          int k = t >> 7, i = t & (n-1);
          int p = pS[k], q = qS[k]; float c = cS[k], s = sS[k];
          float vp = Vt[p*n+i], vq = Vt[q*n+i];
          Vt[p*n+i] = c*vp - s*vq; Vt[q*n+i] = s*vp + c*vq;
        }
      }
      __syncthreads();
    }
    float offs = 0.f, dias = 0.f;
    for (int i = tid; i < n*n; i += 1024) {
      float v = Bs[i];
      if ((i >> 7) == (i & 127)) dias += v*v; else offs += v*v;
    }
    for (int o = 32; o; o >>= 1) { offs += __shfl_down(offs, o); dias += __shfl_down(dias, o); }
    if (lane == 0) { redA[wave] = offs; redB[wave] = dias; }
    __syncthreads();
    if (tid == 0) {
      float oa = 0.f, db = 0.f;
      for (int wv = 0; wv < 16; ++wv) { oa += redA[wv]; db += redB[wv]; }
      done = (oa <= 1e-7f * db + 1e-30f) ? 1 : 0;
    }
    __syncthreads();
    if (done) break;
  }
  // ---- fused post: select top-|w| (wave 0), then write outputs ----
  if (tid < 64) {
    int l2 = tid;
    float v0 = Bs[l2*129], v1 = Bs[(l2+64)*129];
    float a0 = fabsf(v0), a1 = fabsf(v1);
    float ss = 0.f;
    for (int t = 0; t < n; ++t) {
      float b, bv; int bi;
      if (a0 >= a1) { b = a0; bi = l2; bv = v0; }
      else          { b = a1; bi = l2 + 64; bv = v1; }
      for (int o = 32; o; o >>= 1) {
        float ob = __shfl_down(b, o);
        int   oi = __shfl_down(bi, o);
        float ov = __shfl_down(bv, o);
        if (ob > b) { b = ob; bi = oi; bv = ov; }
      }
      bi = __shfl(bi, 0); bv = __shfl(bv, 0);
      if (l2 == 0) {
        idxL[t] = bi;
        if (t < 96) { wsL[t] = bv; ss += bv * bv; }
      }
      if (bi == l2) a0 = -1.f;
      if (bi == l2 + 64) a1 = -1.f;
    }
    if (l2 == 0) wsnL = sqrtf(ss);
  }
  __syncthreads();
  float invn = 1.f / wsnL;
  for (int i = tid; i < 96*96; i += 1024) {
    int r = i / 96, c = i % 96;
    Cmat[i] = (r == c) ? wsL[r] * invn : 0.f;
  }
  for (int i = tid; i < 128*96; i += 1024) {
    int q = i / 96, a = i % 96;
    Vsel[i] = Vt[idxL[a]*n + q];
  }
  for (int i = tid; i < 128*128; i += 1024) {
    int q = i >> 7, t = i & 127;
    Vsrt[i] = Vt[idxL[t]*n + q];
  }
}

// ---------------- observable stage ----------------
__global__ void k_buildK(const float* __restrict__ As, float* __restrict__ K6) {
  int i = blockIdx.x * blockDim.x + threadIdx.x;
  if (i >= 1024) return;
  int y = i & 3, v = (i>>2)&3, x = (i>>4)&3, u = (i>>6)&3, s = (i>>8)&1, p = (i>>9)&1;
  float acc = 0.f;
  for (int w = 0; w < 4; ++w)
    acc += As[((p*4+u)*4+x)*4+w] * As[((s*4+v)*4+y)*4+w];
  K6[i] = acc;
}

__global__ void k_Y1(const float* __restrict__ K6, const float* __restrict__ S, float* __restrict__ Y1) {
  int i = blockIdx.x * blockDim.x + threadIdx.x;
  if (i >= 1024) return;
  int f = i & 3, e = (i>>2)&3, b = (i>>4)&3, a = (i>>6)&3, s = (i>>8)&1, p = (i>>9)&1;
  float acc = 0.f;
  for (int u = 0; u < 4; ++u)
    for (int x = 0; x < 4; ++x)
      for (int v = 0; v < 4; ++v)
        for (int y = 0; y < 4; ++y)
          acc += K6[((((p*2+s)*4+u)*4+x)*4+v)*4+y]
               * S[(((x*4+b)*16 + (v*4+e))*16 + (y*4+f))*16 + (u*4+a)];
  Y1[i] = acc;
}

__global__ void k_W16(const float* __restrict__ K6, const float* __restrict__ Y1, float* __restrict__ W) {
  int i = threadIdx.x;
  if (i >= 16) return;
  int qr = i >> 2, ps = i & 3;
  float acc = 0.f;
  for (int j = 0; j < 256; ++j) acc += K6[qr*256 + j] * Y1[ps*256 + j];
  W[i] = acc;
}

__global__ void k_final(const float* __restrict__ W, const float* __restrict__ H,
                        const float* __restrict__ Ox, const float* __restrict__ Oy,
                        const float* __restrict__ Oz, float* __restrict__ out) {
  if (threadIdx.x != 0 || blockIdx.x != 0) return;
  float Z = 0.f;
  for (int q = 0; q < 2; ++q)
    for (int r = 0; r < 2; ++r) Z += W[((q*2+r)*2+q)*2+r];
  float ln = 0.f;
  for (int i = 0; i < 16; ++i) ln += H[i]*W[i];
  out[0] = ln / Z;
  const float* Os[3] = {Ox, Oy, Oz};
  for (int k = 0; k < 3; ++k) {
    float vA = 0.f, vB = 0.f;
    for (int q = 0; q < 2; ++q)
      for (int p = 0; p < 2; ++p)
        for (int r = 0; r < 2; ++r)
          vA += Os[k][q*2+p] * W[((q*2+r)*2+p)*2+r];
    for (int q = 0; q < 2; ++q)
      for (int r = 0; r < 2; ++r)
        for (int s = 0; s < 2; ++s)
          vB += Os[k][r*2+s] * W[((q*2+r)*2+q)*2+s];
    out[1+k] = 0.5f*(vA+vB)/Z;
  }
}

// ---------------- host ----------------
static inline unsigned nb256(long n) { long b = (n + 255) / 256; return (unsigned)(b < 1 ? 1 : b); }

extern "C" void kernel_launch(void* const* d_in, const int* in_sizes, int n_in,
                              void* d_out, int out_size, void* d_ws, size_t ws_size,
                              hipStream_t stream) {
  const float* A1  = (const float*)d_in[0];
  const float* Hin = (const float*)d_in[1];
  const float* Ox  = (const float*)d_in[2];
  const float* Oy  = (const float*)d_in[3];
  const float* Oz  = (const float*)d_in[4];

  const long SZ_BIG = 1536L*1536L;
  float* p0 = (float*)d_ws;
  float* Asym = p0; p0 += 128;
  float* Tb   = p0; p0 += 4096;
  float* Tvy  = p0; p0 += 4096;
  float* Mb   = p0; p0 += 65536;
  float* Ca   = p0; p0 += CHI*CHI;
  float* Cb   = p0; p0 += CHI*CHI;
  float* Ea   = p0; p0 += CHI*D2T*CHI;
  float* Eb   = p0; p0 += CHI*D2T*CHI;
  float* CE   = p0; p0 += CHI*D2T*CHI;
  float* E2   = p0; p0 += CHI*D2T*CHI;
  float* Pb   = p0; p0 += (CHI*D2T)*CHI;
  float* Xa   = p0; p0 += KSUB*(CHI*D2T);
  float* Xb   = p0; p0 += KSUB*(CHI*D2T);
  float* Vsrt = p0; p0 += KSUB*KSUB;
  float* Lb   = p0; p0 += 16384 + 128;
  float* Part = p0; p0 += 12*KSUB*KSUB;
  float* part = p0; p0 += NBRED;
  float* Vsel = p0; p0 += KSUB*CHI;
  float* K6   = p0; p0 += 1024;
  float* Y1   = p0; p0 += 1024;
  float* W16  = p0; p0 += 16;
  float* tb   = p0; p0 += CHI*D2T*CHI;
  float* ub   = p0; p0 += CHI*D2T*CHI;
  float* Sb   = p0; p0 += 65536;
  float* B1   = p0; p0 += SZ_BIG;
  float* B2   = p0; p0 += SZ_BIG;
  float* B3   = p0; p0 += SZ_BIG;
  if ((size_t)((char*)p0 - (char*)d_ws) > ws_size) return;

  auto normalize = [&](float* a, long n) {
    int nb = (int)((n + 255) / 256); if (nb > NBRED) nb = NBRED;
    k_sumsq<<<nb, 256, 0, stream>>>(a, n, part);
    k_scale_sumsq<<<nb256(n), 256, 0, stream>>>(a, n, part, nb);
  };
  auto gnn = [&](const float* A, const float* B, float* C, int M, int N, int K) {
    dim3 g((N+63)/64, (M+63)/64);
    k_gemm_nn<<<g, 256, 0, stream>>>(A, B, C, M, N, K);
  };
  auto gnnp = [&](const float* A, const float* B, float* C, int M, int N, int K,
                  int Ra, long sa, long sb, int Cbb, long sc, long sd) {
    dim3 g((N+63)/64, (M+63)/64);
    k_gemm_nn_p<<<g, 256, 0, stream>>>(A, B, C, M, N, K, Ra, sa, sb, Cbb, sc, sd);
  };
  auto gtn = [&](const float* A, const float* B, float* C, int M, int N, int K, int sub = 0) {
    dim3 g((N+63)/64, (M+63)/64);
    k_gemm_tn<<<g, 256, 0, stream>>>(A, B, C, M, N, K, sub);
  };
  auto gtnp = [&](const float* A, const float* B, float* C, int M, int N, int K,
                  int Ra, long sa, long sb, int Cbb, long sc, long sd) {
    dim3 g((N+63)/64, (M+63)/64);
    k_gemm_tn_p<<<g, 256, 0, stream>>>(A, B, C, M, N, K, Ra, sa, sb, Cbb, sc, sd);
  };
  // Power multiply Y = X * m via split-K NT (m symmetric => X*m = X*m^T = A*B^T form).
  // Grid up to (48,4,12)=2304 blocks vs 48 blocks of the 64x64 nn path (M=128 is skinny).
  auto powmul = [&](const float* X, const float* m, float* Y, int Nm) {
    int Sk = Nm >> 7;
    dim3 g(Nm/32, 4, Sk);
    k_gnt_splitk<<<g, 256, 0, stream>>>(X, m, B2, KSUB, Nm, Nm);
    k_reduceK<<<nb256((long)KSUB*Nm), 256, 0, stream>>>(B2, Y, (long)KSUB*Nm, Sk);
  };
  // Full-basis CholQR: `passes` x (split-K Gram -> chol128 -> trisolve).
  auto ORTH = [&](float* Y, int Nm, int passes) {
    int Sk = Nm >> 7;
    for (int pass = 0; pass < passes; ++pass) {
      dim3 g(4, 4, Sk);
      k_gnt_splitk<<<g, 256, 0, stream>>>(Y, Y, Part, KSUB, KSUB, Nm);
      k_chol128<<<1, 1024, 0, stream>>>(Part, Sk, Lb);
      k_trisolve128<<<(Nm+15)/16, 1024, 0, stream>>>(Y, Nm, Lb);
    }
  };

  // ---- Stage A ----
  k_symA<<<1, 128, 0, stream>>>(A1, Asym);
  k_buildT<<<16, 256, 0, stream>>>(Asym, Tb);
  normalize(Tb, 4096);
  // Tvy[w][(v,y)] = T[v,y,w]  (rank-16 factorized M-contractions)
  k_perm4<<<16, 256, 0, stream>>>(Tb, Tvy, 16,16,16,1, 1L,256L,16L,0L);
  k_buildM<<<256, 256, 0, stream>>>(Tb, Mb);
  normalize(Mb, 65536);
  k_initC<<<1, 256, 0, stream>>>(Mb, Ca);
  k_sym2d<<<1, 256, 0, stream>>>(Ca, 16);
  normalize(Ca, 256);
  k_initE<<<16, 256, 0, stream>>>(Mb, Ea);
  k_symE_sumsq<<<16, 256, 0, stream>>>(Ea, 16, part);
  k_scale_sumsq<<<nb256(4096), 256, 0, stream>>>(Ea, 4096, part, 16);

  // ---- CTMRG iterations ----
  const int nqs[NITER] = {8, 6, 2, 1, 1, 1, 1, 1, 1, 1, 1, 2};
  float* Ccur = Ca; float* Calt = Cb;
  float* Ecur = Ea; float* Ealt = Eb;
  float* baseB[2] = {Xa, Xb};
  int cur = 0;
  int chic = 16;
  for (int it = 0; it < NITER; ++it) {
    int Nm = chic * D2T;
    int chin = CHI;
    int nq = nqs[it];
    int coldInit = (it <= 1) ? 1 : 0;
    int doRotate = (it >= 1 && it < NITER-1) ? 1 : 0;
    int finalPasses = (it <= 1 || it == NITER-1) ? 2 : 1;
    // ---- Rho build (rank-16 factorized; perms fused into GEMM epilogues) ----
    gnn(Ccur, Ecur, CE, chic, D2T*chic, chic);                                 // CE[a,(x,i)]
    k_perm4<<<nb256((long)chic*chic*16), 256, 0, stream>>>(Ecur, E2,
        chic, chic, 16, 1, 1L, (long)16*chic, (long)chic, 0L);                 // E2[a,(j,u)]
    gtnp(CE, E2, B2, 16*chic, 16*chic, chic,
         chic, (long)chic*256, 16L, 16, 1L, 256L);                             // D1p[(i,j),(x,u)] -> B2
    gnn(B2, Tb, B3, chic*chic, 16, 256);                                       // R[ij,w] = D1p . T
    gnnp(B3, Tvy, B1, chic*chic, 256, 16,
         chic, 16L, (long)256*chic, 16, 1L, (long)16*chic);                    // m[(i,v),(j,y)] -> B1
    float* msym = B1;

    // ---- subspace eigensolve ----
    float* Xc = baseB[cur]; float* Yc = baseB[1-cur];
    if (coldInit)
      k_xinit<<<nb256((long)KSUB*Nm), 256, 0, stream>>>(Xc, KSUB*Nm, 0x9E3779B9u);
    int orthEvery = (it <= 1) ? 4 : 2;
    int since = 0;
    for (int t = 0; t < nq; ++t) {
      powmul(Xc, msym, Yc, Nm);             // Y = X m (split-K, m symmetric)
      { float* tm = Xc; Xc = Yc; Yc = tm; }
      if (++since >= orthEvery || t == nq-1) {
        ORTH(Xc, Nm, (t == nq-1) ? finalPasses : 1);
        since = 0;
      }
    }
    powmul(Xc, msym, Yc, Nm);               // Y2 = X m
    {
      int Sk = Nm >> 7;
      dim3 g(4, 4, Sk);
      k_gnt_splitk<<<g, 256, 0, stream>>>(Yc, Xc, Part, KSUB, KSUB, Nm);   // Bsm partials
      k_jacobi_post<<<1, 1024, 0, stream>>>(Part, Sk, Calt, Vsel, Vsrt, JSWMAX);
    }
    gtn(Xc, Vsel, Pb, Nm, chin, KSUB);      // P (Nm x chin) = Ritz vectors
    if (doRotate) {
      gtn(Vsrt, Xc, Yc, KSUB, Nm, KSUB);    // Xnew = Vsrt^T Xc (orthonormal rotation)
      float* tm = Xc; Xc = Yc; Yc = tm;
    }
    cur = (Xc == Xa) ? 0 : 1;

    // ---- E update (rank-16 factorized; perms fused into GEMM epilogues) ----
    gtnp(Pb, Ecur, B1, D2T*chin, D2T*chic, chic,
         chin, (long)chic*256, 16L, chic, 256L, 1L);                           // T1p[(a,j),(u,x)] -> B1
    gnn(B1, Tb, B3, chin*chic, 16, 256);                                       // R2[aj,w] = T1p . T
    gnnp(B3, Tvy, B2, chin*chic, 256, 16,
         chic, 16L, (long)256*chic, 16, (long)16*chic, 1L);                    // T2p[(a,y),(j,v)] -> B2
    gnn(B2, Pb, Ealt, chin*D2T, chin, chic*D2T);                               // Enew[(a,y),b]
    k_symE_sumsq<<<NBRED, 256, 0, stream>>>(Ealt, chin, part);
    k_scale_sumsq<<<nb256((long)chin*16*chin), 256, 0, stream>>>(Ealt, (long)chin*16*chin, part, NBRED);
    { float* t1 = Ccur; Ccur = Calt; Calt = t1; }
    { float* t1 = Ecur; Ecur = Ealt; Ealt = t1; }
    chic = chin;
  }

  // ---- Environment closure: S_env and observables ----
  gnn(Ccur, Ecur, tb, CHI, D2T*CHI, CHI);                   // t[a,(x,c)]
  gnn(tb, Ccur, ub, CHI*D2T, CHI, CHI);                     // up[(a,x),d]
  gnn(ub, Ecur, B1, CHI*D2T, D2T*CHI, CHI);                 // T1env[(a,x),(v,e)]
  k_perm4<<<nb256(SZ_BIG), 256, 0, stream>>>(B1, B2,
      16, 16, CHI, CHI, 1536L, 96L, 24576L, 1L);            // A'[(X,V),(a,e)]
  k_perm4<<<nb256(SZ_BIG), 256, 0, stream>>>(B1, B3,
      CHI, CHI, 16, 16, 1L, 24576L, 1536L, 96L);            // B'[(a,e),(Y,U)]
  gnn(B2, B3, Sb, 256, 256, CHI*CHI);                       // S[X,V,Y,U]
  k_buildK<<<4, 256, 0, stream>>>(Asym, K6);
  k_Y1<<<4, 256, 0, stream>>>(K6, Sb, Y1);
  k_W16<<<1, 16, 0, stream>>>(K6, Y1, W16);
  k_final<<<1, 1, 0, stream>>>(W16, Hin, Ox, Oy, Oz, (float*)d_out);
}

// Round 18
// 17658.003 us; speedup vs baseline: 1.3991x; 1.1314x over previous
//
#include <hip/hip_runtime.h>
#include <math.h>

#define D2T   16
#define CHI   96
#define NITER 12
#define KSUB  128
#define JSWMAX 12
#define NBRED 128

// ---------------- tiny builders ----------------
__global__ void k_symA(const float* __restrict__ A1, float* __restrict__ As) {
  int i = blockIdx.x * blockDim.x + threadIdx.x;
  if (i >= 128) return;
  int w = i % 4, x = (i / 4) % 4, u = (i / 16) % 4, p = i / 64;
#define AT(pp,aa,bb,cc) A1[(((pp)*4+(aa))*4+(bb))*4+(cc)]
  As[i] = AT(p,u,x,w) + AT(p,u,w,x) + AT(p,x,w,u) + AT(p,w,x,u) + AT(p,w,u,x) + AT(p,x,u,w);
#undef AT
}

__global__ void k_buildT(const float* __restrict__ As, float* __restrict__ T) {
  int i = blockIdx.x * blockDim.x + threadIdx.x;
  if (i >= 4096) return;
  int Wf = i % 16, Xf = (i / 16) % 16, Uf = i / 256;
  int u = Uf >> 2, a = Uf & 3, x = Xf >> 2, b = Xf & 3, w = Wf >> 2, c = Wf & 3;
  float s = 0.f;
  for (int p = 0; p < 2; ++p)
    s += As[((p*4+u)*4+x)*4+w] * As[((p*4+a)*4+b)*4+c];
  T[i] = s;
}

__global__ void k_buildM(const float* __restrict__ T, float* __restrict__ M) {
  int i = blockIdx.x * blockDim.x + threadIdx.x;
  if (i >= 65536) return;
  int y = i % 16, x = (i / 16) % 16, v = (i / 256) % 16, u = i / 4096;
  const float* Tu = T + (u*16 + x)*16;
  const float* Tv = T + (v*16 + y)*16;
  float s = 0.f;
  for (int w = 0; w < 16; ++w) s += Tu[w]*Tv[w];
  M[i] = s;
}

__global__ void k_initC(const float* __restrict__ M, float* __restrict__ C) {
  int i = blockIdx.x * blockDim.x + threadIdx.x;
  if (i >= 256) return;
  int v = i / 16, y = i % 16;
  float s = 0.f;
  for (int u = 0; u < 16; ++u)
    for (int x = 0; x < 16; ++x)
      s += M[((u*16+v)*16+x)*16+y];
  C[v*16+y] = s;
}

__global__ void k_initE(const float* __restrict__ M, float* __restrict__ E) {
  int i = blockIdx.x * blockDim.x + threadIdx.x;
  if (i >= 4096) return;
  int v = i % 16, y = (i / 16) % 16, u = i / 256;
  float s = 0.f;
  for (int x = 0; x < 16; ++x) s += M[((u*16+v)*16+x)*16+y];
  E[(u*16+y)*16+v] = s;   // E[u][y][v], chic=16
}

// ---------------- generic helpers ----------------
__global__ void k_perm4(const float* __restrict__ src, float* __restrict__ dst,
                        int d0, int d1, int d2, int d3,
                        long s0, long s1, long s2, long s3) {
  long n = (long)d0 * d1 * d2 * d3;
  for (long i = blockIdx.x * (long)blockDim.x + threadIdx.x; i < n;
       i += (long)gridDim.x * blockDim.x) {
    int i3 = (int)(i % d3); long t = i / d3;
    int i2 = (int)(t % d2); t /= d2;
    int i1 = (int)(t % d1); int i0 = (int)(t / d1);
    dst[i] = src[i0*s0 + i1*s1 + i2*s2 + i3*s3];
  }
}

__global__ void k_sym2d(float* __restrict__ A, int n) {
  long nn = (long)n * n;
  for (long i = blockIdx.x * (long)blockDim.x + threadIdx.x; i < nn;
       i += (long)gridDim.x * blockDim.x) {
    int r = (int)(i / n), c = (int)(i % n);
    if (r <= c) {
      float v = 0.5f * (A[(long)r*n + c] + A[(long)c*n + r]);
      A[(long)r*n + c] = v; A[(long)c*n + r] = v;
    }
  }
}

// fused: symmetrize E (a<=b pairs) AND accumulate ||E||^2 partials (off-diag counted twice)
__global__ void k_symE_sumsq(float* __restrict__ E, int chi, float* __restrict__ partial) {
  __shared__ float red[256];
  long n = (long)chi * 16 * chi;
  float s = 0.f;
  for (long i = blockIdx.x * (long)blockDim.x + threadIdx.x; i < n;
       i += (long)gridDim.x * blockDim.x) {
    int b = (int)(i % chi); long t = i / chi;
    int y = (int)(t % 16); int a = (int)(t / 16);
    if (a <= b) {
      long ia = ((long)a*16 + y)*chi + b, ib = ((long)b*16 + y)*chi + a;
      float v = 0.5f * (E[ia] + E[ib]);
      E[ia] = v; E[ib] = v;
      s += (a == b) ? v*v : 2.f*v*v;
    }
  }
  red[threadIdx.x] = s; __syncthreads();
  for (int o = 128; o; o >>= 1) { if ((int)threadIdx.x < o) red[threadIdx.x] += red[threadIdx.x + o]; __syncthreads(); }
  if (threadIdx.x == 0) partial[blockIdx.x] = red[0];
}

__global__ void k_sumsq(const float* __restrict__ a, long n, float* __restrict__ partial) {
  __shared__ float red[256];
  float s = 0.f;
  for (long i = blockIdx.x * 256L + threadIdx.x; i < n; i += (long)gridDim.x * 256L) {
    float v = a[i]; s += v*v;
  }
  red[threadIdx.x] = s; __syncthreads();
  for (int o = 128; o; o >>= 1) { if ((int)threadIdx.x < o) red[threadIdx.x] += red[threadIdx.x + o]; __syncthreads(); }
  if (threadIdx.x == 0) partial[blockIdx.x] = red[0];
}

__global__ void k_scale_sumsq(float* __restrict__ a, long n,
                              const float* __restrict__ partial, int nb) {
  __shared__ float red[256];
  float s = 0.f;
  for (int i = threadIdx.x; i < nb; i += 256) s += partial[i];
  red[threadIdx.x] = s; __syncthreads();
  for (int o = 128; o; o >>= 1) { if ((int)threadIdx.x < o) red[threadIdx.x] += red[threadIdx.x + o]; __syncthreads(); }
  float f = rsqrtf(red[0]);
  for (long i = blockIdx.x * (long)blockDim.x + threadIdx.x; i < n;
       i += (long)gridDim.x * blockDim.x) a[i] *= f;
}

__global__ void k_reduceK(const float* __restrict__ in, float* __restrict__ out, long mn, int S) {
  for (long i = blockIdx.x * (long)blockDim.x + threadIdx.x; i < mn;
       i += (long)gridDim.x * blockDim.x) {
    float s = 0.f;
    for (int z = 0; z < S; ++z) s += in[(long)z*mn + i];
    out[i] = s;
  }
}

// ---------------- GEMMs (fp32, 64x64 tile, 256 thr, 4x4/thr) ----------------
__global__ __launch_bounds__(256) void k_gemm_nn(const float* __restrict__ A, const float* __restrict__ B,
                                                 float* __restrict__ C, int M, int N, int K) {
  __shared__ float As[16][68];
  __shared__ float Bs[16][68];
  int tid = threadIdx.x, tx = tid % 16, ty = tid / 16;
  int row0 = blockIdx.y*64, col0 = blockIdx.x*64;
  float acc[4][4] = {};
  for (int k0 = 0; k0 < K; k0 += 16) {
    for (int i = tid; i < 16*64; i += 256) {
      int c = i % 16, r = i / 16;
      float v = 0.f;
      if (row0 + r < M && k0 + c < K) v = A[(long)(row0+r)*K + k0 + c];
      As[c][r] = v;
    }
    for (int i = tid; i < 16*64; i += 256) {
      int c = i % 64, r = i / 64;
      float v = 0.f;
      if (k0 + r < K && col0 + c < N) v = B[(long)(k0+r)*N + col0 + c];
      Bs[r][c] = v;
    }
    __syncthreads();
    for (int kk = 0; kk < 16; ++kk) {
      float av[4], bv[4];
#pragma unroll
      for (int ii = 0; ii < 4; ++ii) av[ii] = As[kk][ty*4+ii];
#pragma unroll
      for (int jj = 0; jj < 4; ++jj) bv[jj] = Bs[kk][tx*4+jj];
#pragma unroll
      for (int ii = 0; ii < 4; ++ii)
#pragma unroll
        for (int jj = 0; jj < 4; ++jj) acc[ii][jj] += av[ii]*bv[jj];
    }
    __syncthreads();
  }
  for (int ii = 0; ii < 4; ++ii) {
    int r = row0 + ty*4 + ii;
    if (r >= M) continue;
    for (int jj = 0; jj < 4; ++jj) {
      int c = col0 + tx*4 + jj;
      if (c < N) C[(long)r*N + c] = acc[ii][jj];
    }
  }
}

// nn GEMM with permuted output: dst = (r%Ra)*sa + (r/Ra)*sb + (c%Cb)*sc + (c/Cb)*sd
__global__ __launch_bounds__(256) void k_gemm_nn_p(const float* __restrict__ A, const float* __restrict__ B,
                                                   float* __restrict__ C, int M, int N, int K,
                                                   int Ra, long sa, long sb, int Cb, long sc, long sd) {
  __shared__ float As[16][68];
  __shared__ float Bs[16][68];
  int tid = threadIdx.x, tx = tid % 16, ty = tid / 16;
  int row0 = blockIdx.y*64, col0 = blockIdx.x*64;
  float acc[4][4] = {};
  for (int k0 = 0; k0 < K; k0 += 16) {
    for (int i = tid; i < 16*64; i += 256) {
      int c = i % 16, r = i / 16;
      float v = 0.f;
      if (row0 + r < M && k0 + c < K) v = A[(long)(row0+r)*K + k0 + c];
      As[c][r] = v;
    }
    for (int i = tid; i < 16*64; i += 256) {
      int c = i % 64, r = i / 64;
      float v = 0.f;
      if (k0 + r < K && col0 + c < N) v = B[(long)(k0+r)*N + col0 + c];
      Bs[r][c] = v;
    }
    __syncthreads();
    for (int kk = 0; kk < 16; ++kk) {
      float av[4], bv[4];
#pragma unroll
      for (int ii = 0; ii < 4; ++ii) av[ii] = As[kk][ty*4+ii];
#pragma unroll
      for (int jj = 0; jj < 4; ++jj) bv[jj] = Bs[kk][tx*4+jj];
#pragma unroll
      for (int ii = 0; ii < 4; ++ii)
#pragma unroll
        for (int jj = 0; jj < 4; ++jj) acc[ii][jj] += av[ii]*bv[jj];
    }
    __syncthreads();
  }
  for (int ii = 0; ii < 4; ++ii) {
    int r = row0 + ty*4 + ii;
    if (r >= M) continue;
    long ro = (long)(r % Ra)*sa + (long)(r / Ra)*sb;
    for (int jj = 0; jj < 4; ++jj) {
      int c = col0 + tx*4 + jj;
      if (c < N) C[ro + (long)(c % Cb)*sc + (long)(c / Cb)*sd] = acc[ii][jj];
    }
  }
}

// C = A^T B (sub=0) or C -= A^T B (sub=1); A is (K x M) row-major, B is (K x N) row-major
__global__ __launch_bounds__(256) void k_gemm_tn(const float* __restrict__ A, const float* __restrict__ B,
                                                 float* __restrict__ C, int M, int N, int K, int sub) {
  __shared__ float As[16][68];
  __shared__ float Bs[16][68];
  int tid = threadIdx.x, tx = tid % 16, ty = tid / 16;
  int row0 = blockIdx.y*64, col0 = blockIdx.x*64;
  float acc[4][4] = {};
  for (int k0 = 0; k0 < K; k0 += 16) {
    for (int i = tid; i < 16*64; i += 256) {
      int r = i % 64, kk = i / 64;
      float v = 0.f;
      if (k0 + kk < K && row0 + r < M) v = A[(long)(k0+kk)*M + row0 + r];
      As[kk][r] = v;
    }
    for (int i = tid; i < 16*64; i += 256) {
      int c = i % 64, kk = i / 64;
      float v = 0.f;
      if (k0 + kk < K && col0 + c < N) v = B[(long)(k0+kk)*N + col0 + c];
      Bs[kk][c] = v;
    }
    __syncthreads();
    for (int kk = 0; kk < 16; ++kk) {
      float av[4], bv[4];
#pragma unroll
      for (int ii = 0; ii < 4; ++ii) av[ii] = As[kk][ty*4+ii];
#pragma unroll
      for (int jj = 0; jj < 4; ++jj) bv[jj] = Bs[kk][tx*4+jj];
#pragma unroll
      for (int ii = 0; ii < 4; ++ii)
#pragma unroll
        for (int jj = 0; jj < 4; ++jj) acc[ii][jj] += av[ii]*bv[jj];
    }
    __syncthreads();
  }
  for (int ii = 0; ii < 4; ++ii) {
    int r = row0 + ty*4 + ii;
    if (r >= M) continue;
    for (int jj = 0; jj < 4; ++jj) {
      int c = col0 + tx*4 + jj;
      if (c < N) {
        if (sub) C[(long)r*N + c] -= acc[ii][jj];
        else     C[(long)r*N + c]  = acc[ii][jj];
      }
    }
  }
}

// tn GEMM with permuted output (same dst mapping as nn_p)
__global__ __launch_bounds__(256) void k_gemm_tn_p(const float* __restrict__ A, const float* __restrict__ B,
                                                   float* __restrict__ C, int M, int N, int K,
                                                   int Ra, long sa, long sb, int Cb, long sc, long sd) {
  __shared__ float As[16][68];
  __shared__ float Bs[16][68];
  int tid = threadIdx.x, tx = tid % 16, ty = tid / 16;
  int row0 = blockIdx.y*64, col0 = blockIdx.x*64;
  float acc[4][4] = {};
  for (int k0 = 0; k0 < K; k0 += 16) {
    for (int i = tid; i < 16*64; i += 256) {
      int r = i % 64, kk = i / 64;
      float v = 0.f;
      if (k0 + kk < K && row0 + r < M) v = A[(long)(k0+kk)*M + row0 + r];
      As[kk][r] = v;
    }
    for (int i = tid; i < 16*64; i += 256) {
      int c = i % 64, kk = i / 64;
      float v = 0.f;
      if (k0 + kk < K && col0 + c < N) v = B[(long)(k0+kk)*N + col0 + c];
      Bs[kk][c] = v;
    }
    __syncthreads();
    for (int kk = 0; kk < 16; ++kk) {
      float av[4], bv[4];
#pragma unroll
      for (int ii = 0; ii < 4; ++ii) av[ii] = As[kk][ty*4+ii];
#pragma unroll
      for (int jj = 0; jj < 4; ++jj) bv[jj] = Bs[kk][tx*4+jj];
#pragma unroll
      for (int ii = 0; ii < 4; ++ii)
#pragma unroll
        for (int jj = 0; jj < 4; ++jj) acc[ii][jj] += av[ii]*bv[jj];
    }
    __syncthreads();
  }
  for (int ii = 0; ii < 4; ++ii) {
    int r = row0 + ty*4 + ii;
    if (r >= M) continue;
    long ro = (long)(r % Ra)*sa + (long)(r / Ra)*sb;
    for (int jj = 0; jj < 4; ++jj) {
      int c = col0 + tx*4 + jj;
      if (c < N) C[ro + (long)(c % Cb)*sc + (long)(c / Cb)*sd] = acc[ii][jj];
    }
  }
}

// Split-K  Cpart[z] = A(M x K) B(N x K)^T over K-chunk z (128 wide). Tile 32x32, 2x2/thr.
__global__ __launch_bounds__(256) void k_gnt_splitk(const float* __restrict__ A, const float* __restrict__ B,
                                                    float* __restrict__ Cp, int M, int N, int K) {
  __shared__ float As[16][33];
  __shared__ float Bs[16][33];
  int tid = threadIdx.x, tx = tid % 16, ty = tid / 16;
  int row0 = blockIdx.y*32, col0 = blockIdx.x*32;
  int z = blockIdx.z;
  int kbeg = z*128, kend = kbeg + 128 < K ? kbeg + 128 : K;
  float acc[2][2] = {};
  for (int k0 = kbeg; k0 < kend; k0 += 16) {
    for (int i = tid; i < 512; i += 256) {
      int kk = i & 15, r = i >> 4;
      float v = 0.f;
      if (row0 + r < M && k0 + kk < K) v = A[(long)(row0+r)*K + k0 + kk];
      As[kk][r] = v;
    }
    for (int i = tid; i < 512; i += 256) {
      int kk = i & 15, c = i >> 4;
      float v = 0.f;
      if (col0 + c < N && k0 + kk < K) v = B[(long)(col0+c)*K + k0 + kk];
      Bs[kk][c] = v;
    }
    __syncthreads();
    for (int kk = 0; kk < 16; ++kk) {
      float a0 = As[kk][ty*2], a1 = As[kk][ty*2+1];
      float b0 = Bs[kk][tx*2], b1 = Bs[kk][tx*2+1];
      acc[0][0] += a0*b0; acc[0][1] += a0*b1;
      acc[1][0] += a1*b0; acc[1][1] += a1*b1;
    }
    __syncthreads();
  }
  long base = (long)z * M * N;
  for (int ii = 0; ii < 2; ++ii) {
    int r = row0 + ty*2 + ii;
    if (r >= M) continue;
    for (int jj = 0; jj < 2; ++jj) {
      int c = col0 + tx*2 + jj;
      if (c < N) Cp[base + (long)r*N + c] = acc[ii][jj];
    }
  }
}

// ---------------- subspace iteration pieces ----------------
__global__ void k_xinit(float* __restrict__ X, int n, unsigned seed) {
  int i = blockIdx.x * blockDim.x + threadIdx.x;
  if (i >= n) return;
  unsigned x = (unsigned)i * 2654435761u + seed;
  x ^= x >> 16; x *= 2246822519u; x ^= x >> 13; x *= 3266489917u; x ^= x >> 16;
  X[i] = (float)x * (1.0f/4294967296.0f) - 0.5f;
}

// Reduce split-K Gram partials (128x128) -> Cholesky with clamped pivots -> Lout + flags.
__global__ __launch_bounds__(1024) void k_chol128(const float* __restrict__ Part, int nkz,
                                                  float* __restrict__ Lout) {
  __shared__ float G[128*129];
  __shared__ int flags[128];
  __shared__ float dminS;
  int tid = threadIdx.x;
  for (int i = tid; i < 16384; i += 1024) {
    float s = 0.f;
    for (int z = 0; z < nkz; ++z) s += Part[(long)z*16384 + i];
    G[(i >> 7)*129 + (i & 127)] = s;
  }
  __syncthreads();
  if (tid == 0) {
    float tr = 0.f;
    for (int i = 0; i < 128; ++i) tr += G[i*129+i];
    dminS = tr * (1e-12f/128.f) + 1e-30f;
  }
  __syncthreads();
  int ty = tid >> 5, tx = tid & 31;
  for (int k = 0; k < 128; ++k) {
    if (tid == 0) {
      float d = G[k*129+k];
      int bad = (d < dminS) ? 1 : 0;
      flags[k] = bad;
      G[k*129+k] = sqrtf(bad ? dminS : d);
    }
    __syncthreads();
    float lkk = G[k*129+k];
    int bad = flags[k];
    for (int i = k+1+tid; i < 128; i += 1024)
      G[i*129+k] = bad ? 0.f : (G[i*129+k] / lkk);
    __syncthreads();
    for (int i = k+1+ty; i < 128; i += 32)
      for (int j = k+1+tx; j <= i; j += 32)
        G[i*129+j] -= G[i*129+k] * G[j*129+k];
    __syncthreads();
  }
  for (int i = tid; i < 16384; i += 1024) Lout[i] = G[(i>>7)*129 + (i&127)];
  if (tid < 128) ((int*)Lout)[16384 + tid] = flags[tid];
}

// X (128 x Nm) <- L^{-1} X. One wave per column; L in LDS. Clamped rows re-seeded with noise.
__global__ __launch_bounds__(1024) void k_trisolve128(float* __restrict__ X, int Nm,
                                                      const float* __restrict__ Lin) {
  __shared__ float Ls[128*129];
  __shared__ int flags[128];
  int tid = threadIdx.x, wave = tid >> 6, lane = tid & 63;
  for (int i = tid; i < 16384; i += 1024) Ls[(i>>7)*129 + (i&127)] = Lin[i];
  if (tid < 128) flags[tid] = ((const int*)Lin)[16384 + tid];
  __syncthreads();
  int c = blockIdx.x*16 + wave;
  if (c >= Nm) return;
  float v0 = X[(long)lane*Nm + c];
  float v1 = X[(long)(lane+64)*Nm + c];
  for (int i = 0; i < 128; ++i) {
    float l0 = Ls[i*129 + lane];
    float l1 = Ls[i*129 + lane + 64];
    float partial = 0.f;
    if (lane < i) partial += l0 * v0;
    if (lane + 64 < i) partial += l1 * v1;
    for (int o = 32; o; o >>= 1) partial += __shfl_down(partial, o);
    float s = __shfl(partial, 0);
    float lii = Ls[i*129 + i];
    int bad = flags[i];
    unsigned h = (unsigned)(i*1315423911u) ^ (unsigned)(c*2654435761u);
    h ^= h >> 16; h *= 2246822519u; h ^= h >> 13;
    float noise = ((float)h * (1.0f/4294967296.0f) - 0.5f) * 1e-3f;
    if (i < 64) {
      if (lane == i)      v0 = bad ? noise : ((v0 - s) / lii);
    } else {
      if (lane == i - 64) v1 = bad ? noise : ((v1 - s) / lii);
    }
  }
  X[(long)lane*Nm + c] = v0;
  X[(long)(lane+64)*Nm + c] = v1;
}

// Jacobi 128x128 from split-K partials (fused reduce+symmetrize on load), early-exit,
// THRESHOLD-SKIP rounds, then fused post: |w|-select + C diag + Vsel + Vsrt.
__global__ __launch_bounds__(1024) void k_jacobi_post(const float* __restrict__ Part, int nkz,
                                                      float* __restrict__ Cmat, float* __restrict__ Vsel,
                                                      float* __restrict__ Vsrt, int maxsweeps) {
  const int n = KSUB;
  __shared__ float Bs[KSUB*KSUB];
  __shared__ float Vt[KSUB*KSUB];
  __shared__ float cS[64], sS[64];
  __shared__ int pS[64], qS[64];
  __shared__ float redA[16], redB[16];
  __shared__ int done;
  __shared__ int skipF;
  __shared__ float thrS;
  __shared__ int idxL[128];
  __shared__ float wsL[96];
  __shared__ float wsnL;
  int tid = threadIdx.x, wave = tid >> 6, lane = tid & 63;
  for (int i = tid; i < n*n; i += 1024) {
    int r = i >> 7, c = i & 127;
    float s1 = 0.f, s2 = 0.f;
    for (int z = 0; z < nkz; ++z) {
      s1 += Part[(long)z*16384 + i];
      s2 += Part[(long)z*16384 + c*128 + r];
    }
    Bs[i] = 0.5f*(s1 + s2);
    Vt[i] = (r == c) ? 1.f : 0.f;
  }
  if (tid == 0) done = 0;
  __syncthreads();
  {
    float dias = 0.f;
    for (int i = tid; i < n*n; i += 1024) {
      if ((i >> 7) == (i & 127)) { float v = Bs[i]; dias += v*v; }
    }
    for (int o = 32; o; o >>= 1) dias += __shfl_down(dias, o);
    if (lane == 0) redB[wave] = dias;
    __syncthreads();
    if (tid == 0) {
      float db = 0.f;
      for (int wv = 0; wv < 16; ++wv) db += redB[wv];
      thrS = 3e-6f * sqrtf(db / 128.f);
    }
    __syncthreads();
  }
  for (int sw = 0; sw < maxsweeps; ++sw) {
    for (int r = 0; r < n-1; ++r) {
      float myb = 0.f;
      if (tid < 64) {
        int k = tid, a, b;
        if (k == 0) { a = n-1; b = r % (n-1); }
        else { a = (r + k) % (n-1); b = (r - k + (n-1)) % (n-1); }
        int p = a < b ? a : b, q = a < b ? b : a;
        float bpp = Bs[p*n+p], bqq = Bs[q*n+q], bpq = Bs[p*n+q];
        float c = 1.f, s = 0.f;
        if (bpq != 0.f) {
          float tau = (bqq - bpp) / (2.f*bpq);
          float t = (tau >= 0.f ? 1.f : -1.f) / (fabsf(tau) + sqrtf(1.f + tau*tau));
          c = rsqrtf(1.f + t*t); s = t*c;
        }
        pS[k] = p; qS[k] = q; cS[k] = c; sS[k] = s;
        myb = fabsf(bpq);
      }
      if (tid < 64) {
        for (int o = 32; o; o >>= 1) { float ob = __shfl_down(myb, o); if (ob > myb) myb = ob; }
        if (tid == 0) skipF = (myb <= thrS) ? 1 : 0;
      }
      __syncthreads();
      if (!skipF) {
        for (int t = tid; t < 64*64; t += 1024) {
          int k1 = t >> 6, k2 = t & 63;
          int p1 = pS[k1], q1 = qS[k1]; float c1 = cS[k1], s1 = sS[k1];
          int p2 = pS[k2], q2 = qS[k2]; float c2 = cS[k2], s2 = sS[k2];
          float a = Bs[p1*n+p2], b = Bs[p1*n+q2], d = Bs[q1*n+p2], e = Bs[q1*n+q2];
          float a1 = c1*a - s1*d, b1 = c1*b - s1*e;
          float d1 = s1*a + c1*d, e1 = s1*b + c1*e;
          Bs[p1*n+p2] = c2*a1 - s2*b1; Bs[p1*n+q2] = s2*a1 + c2*b1;
          Bs[q1*n+p2] = c2*d1 - s2*e1; Bs[q1*n+q2] = s2*d1 + c2*e1;
        }
        for (int t = tid; t < 64*n; t += 1024) {
          int k = t >> 7, i = t & (n-1);
          int p = pS[k], q = qS[k]; float c = cS[k], s = sS[k];
          float vp = Vt[p*n+i], vq = Vt[q*n+i];
          Vt[p*n+i] = c*vp - s*vq; Vt[q*n+i] = s*vp + c*vq;
        }
      }
      __syncthreads();
    }
    float offs = 0.f, dias = 0.f;
    for (int i = tid; i < n*n; i += 1024) {
      float v = Bs[i];
      if ((i >> 7) == (i & 127)) dias += v*v; else offs += v*v;
    }
    for (int o = 32; o; o >>= 1) { offs += __shfl_down(offs, o); dias += __shfl_down(dias, o); }
    if (lane == 0) { redA[wave] = offs; redB[wave] = dias; }
    __syncthreads();
    if (tid == 0) {
      float oa = 0.f, db = 0.f;
      for (int wv = 0; wv < 16; ++wv) { oa += redA[wv]; db += redB[wv]; }
      done = (oa <= 1e-7f * db + 1e-30f) ? 1 : 0;
    }
    __syncthreads();
    if (done) break;
  }
  // ---- fused post: select top-|w| (wave 0), then write outputs ----
  if (tid < 64) {
    int l2 = tid;
    float v0 = Bs[l2*129], v1 = Bs[(l2+64)*129];
    float a0 = fabsf(v0), a1 = fabsf(v1);
    float ss = 0.f;
    for (int t = 0; t < n; ++t) {
      float b, bv; int bi;
      if (a0 >= a1) { b = a0; bi = l2; bv = v0; }
      else          { b = a1; bi = l2 + 64; bv = v1; }
      for (int o = 32; o; o >>= 1) {
        float ob = __shfl_down(b, o);
        int   oi = __shfl_down(bi, o);
        float ov = __shfl_down(bv, o);
        if (ob > b) { b = ob; bi = oi; bv = ov; }
      }
      bi = __shfl(bi, 0); bv = __shfl(bv, 0);
      if (l2 == 0) {
        idxL[t] = bi;
        if (t < 96) { wsL[t] = bv; ss += bv * bv; }
      }
      if (bi == l2) a0 = -1.f;
      if (bi == l2 + 64) a1 = -1.f;
    }
    if (l2 == 0) wsnL = sqrtf(ss);
  }
  __syncthreads();
  float invn = 1.f / wsnL;
  for (int i = tid; i < 96*96; i += 1024) {
    int r = i / 96, c = i % 96;
    Cmat[i] = (r == c) ? wsL[r] * invn : 0.f;
  }
  for (int i = tid; i < 128*96; i += 1024) {
    int q = i / 96, a = i % 96;
    Vsel[i] = Vt[idxL[a]*n + q];
  }
  for (int i = tid; i < 128*128; i += 1024) {
    int q = i >> 7, t = i & 127;
    Vsrt[i] = Vt[idxL[t]*n + q];
  }
}

// ---------------- observable stage ----------------
__global__ void k_buildK(const float* __restrict__ As, float* __restrict__ K6) {
  int i = blockIdx.x * blockDim.x + threadIdx.x;
  if (i >= 1024) return;
  int y = i & 3, v = (i>>2)&3, x = (i>>4)&3, u = (i>>6)&3, s = (i>>8)&1, p = (i>>9)&1;
  float acc = 0.f;
  for (int w = 0; w < 4; ++w)
    acc += As[((p*4+u)*4+x)*4+w] * As[((s*4+v)*4+y)*4+w];
  K6[i] = acc;
}

__global__ void k_Y1(const float* __restrict__ K6, const float* __restrict__ S, float* __restrict__ Y1) {
  int i = blockIdx.x * blockDim.x + threadIdx.x;
  if (i >= 1024) return;
  int f = i & 3, e = (i>>2)&3, b = (i>>4)&3, a = (i>>6)&3, s = (i>>8)&1, p = (i>>9)&1;
  float acc = 0.f;
  for (int u = 0; u < 4; ++u)
    for (int x = 0; x < 4; ++x)
      for (int v = 0; v < 4; ++v)
        for (int y = 0; y < 4; ++y)
          acc += K6[((((p*2+s)*4+u)*4+x)*4+v)*4+y]
               * S[(((x*4+b)*16 + (v*4+e))*16 + (y*4+f))*16 + (u*4+a)];
  Y1[i] = acc;
}

__global__ void k_W16(const float* __restrict__ K6, const float* __restrict__ Y1, float* __restrict__ W) {
  int i = threadIdx.x;
  if (i >= 16) return;
  int qr = i >> 2, ps = i & 3;
  float acc = 0.f;
  for (int j = 0; j < 256; ++j) acc += K6[qr*256 + j] * Y1[ps*256 + j];
  W[i] = acc;
}

__global__ void k_final(const float* __restrict__ W, const float* __restrict__ H,
                        const float* __restrict__ Ox, const float* __restrict__ Oy,
                        const float* __restrict__ Oz, float* __restrict__ out) {
  if (threadIdx.x != 0 || blockIdx.x != 0) return;
  float Z = 0.f;
  for (int q = 0; q < 2; ++q)
    for (int r = 0; r < 2; ++r) Z += W[((q*2+r)*2+q)*2+r];
  float ln = 0.f;
  for (int i = 0; i < 16; ++i) ln += H[i]*W[i];
  out[0] = ln / Z;
  const float* Os[3] = {Ox, Oy, Oz};
  for (int k = 0; k < 3; ++k) {
    float vA = 0.f, vB = 0.f;
    for (int q = 0; q < 2; ++q)
      for (int p = 0; p < 2; ++p)
        for (int r = 0; r < 2; ++r)
          vA += Os[k][q*2+p] * W[((q*2+r)*2+p)*2+r];
    for (int q = 0; q < 2; ++q)
      for (int r = 0; r < 2; ++r)
        for (int s = 0; s < 2; ++s)
          vB += Os[k][r*2+s] * W[((q*2+r)*2+q)*2+s];
    out[1+k] = 0.5f*(vA+vB)/Z;
  }
}

// ---------------- host ----------------
static inline unsigned nb256(long n) { long b = (n + 255) / 256; return (unsigned)(b < 1 ? 1 : b); }

extern "C" void kernel_launch(void* const* d_in, const int* in_sizes, int n_in,
                              void* d_out, int out_size, void* d_ws, size_t ws_size,
                              hipStream_t stream) {
  const float* A1  = (const float*)d_in[0];
  const float* Hin = (const float*)d_in[1];
  const float* Ox  = (const float*)d_in[2];
  const float* Oy  = (const float*)d_in[3];
  const float* Oz  = (const float*)d_in[4];

  const long SZ_BIG = 1536L*1536L;
  float* p0 = (float*)d_ws;
  float* Asym = p0; p0 += 128;
  float* Tb   = p0; p0 += 4096;
  float* Tvy  = p0; p0 += 4096;
  float* Mb   = p0; p0 += 65536;
  float* Ca   = p0; p0 += CHI*CHI;
  float* Cb   = p0; p0 += CHI*CHI;
  float* Ea   = p0; p0 += CHI*D2T*CHI;
  float* Eb   = p0; p0 += CHI*D2T*CHI;
  float* CE   = p0; p0 += CHI*D2T*CHI;
  float* E2   = p0; p0 += CHI*D2T*CHI;
  float* Pb   = p0; p0 += (CHI*D2T)*CHI;
  float* Pt   = p0; p0 += CHI*(CHI*D2T);
  float* Xa   = p0; p0 += KSUB*(CHI*D2T);
  float* Xb   = p0; p0 += KSUB*(CHI*D2T);
  float* Vsrt = p0; p0 += KSUB*KSUB;
  float* Lb   = p0; p0 += 16384 + 128;
  float* Part = p0; p0 += 12*KSUB*KSUB;
  float* part = p0; p0 += NBRED;
  float* Vsel = p0; p0 += KSUB*CHI;
  float* K6   = p0; p0 += 1024;
  float* Y1   = p0; p0 += 1024;
  float* W16  = p0; p0 += 16;
  float* tb   = p0; p0 += CHI*D2T*CHI;
  float* ub   = p0; p0 += CHI*D2T*CHI;
  float* Sb   = p0; p0 += 65536;
  float* B1   = p0; p0 += SZ_BIG;
  float* B2   = p0; p0 += SZ_BIG;
  float* B3   = p0; p0 += SZ_BIG;
  if ((size_t)((char*)p0 - (char*)d_ws) > ws_size) return;

  auto normalize = [&](float* a, long n) {
    int nb = (int)((n + 255) / 256); if (nb > NBRED) nb = NBRED;
    k_sumsq<<<nb, 256, 0, stream>>>(a, n, part);
    k_scale_sumsq<<<nb256(n), 256, 0, stream>>>(a, n, part, nb);
  };
  auto gnn = [&](const float* A, const float* B, float* C, int M, int N, int K) {
    dim3 g((N+63)/64, (M+63)/64);
    k_gemm_nn<<<g, 256, 0, stream>>>(A, B, C, M, N, K);
  };
  auto gnnp = [&](const float* A, const float* B, float* C, int M, int N, int K,
                  int Ra, long sa, long sb, int Cbb, long sc, long sd) {
    dim3 g((N+63)/64, (M+63)/64);
    k_gemm_nn_p<<<g, 256, 0, stream>>>(A, B, C, M, N, K, Ra, sa, sb, Cbb, sc, sd);
  };
  auto gtn = [&](const float* A, const float* B, float* C, int M, int N, int K, int sub = 0) {
    dim3 g((N+63)/64, (M+63)/64);
    k_gemm_tn<<<g, 256, 0, stream>>>(A, B, C, M, N, K, sub);
  };
  auto gtnp = [&](const float* A, const float* B, float* C, int M, int N, int K,
                  int Ra, long sa, long sb, int Cbb, long sc, long sd) {
    dim3 g((N+63)/64, (M+63)/64);
    k_gemm_tn_p<<<g, 256, 0, stream>>>(A, B, C, M, N, K, Ra, sa, sb, Cbb, sc, sd);
  };
  // Power multiply Y = X * m via split-K NT (m symmetric => X*m = X*m^T).
  auto powmul = [&](const float* X, const float* m, float* Y, int Nm) {
    int Sk = Nm >> 7;
    dim3 g(Nm/32, 4, Sk);
    k_gnt_splitk<<<g, 256, 0, stream>>>(X, m, B2, KSUB, Nm, Nm);
    k_reduceK<<<nb256((long)KSUB*Nm), 256, 0, stream>>>(B2, Y, (long)KSUB*Nm, Sk);
  };
  // Full-basis CholQR: `passes` x (split-K Gram -> chol128 -> trisolve).
  auto ORTH = [&](float* Y, int Nm, int passes) {
    int Sk = Nm >> 7;
    for (int pass = 0; pass < passes; ++pass) {
      dim3 g(4, 4, Sk);
      k_gnt_splitk<<<g, 256, 0, stream>>>(Y, Y, Part, KSUB, KSUB, Nm);
      k_chol128<<<1, 1024, 0, stream>>>(Part, Sk, Lb);
      k_trisolve128<<<(Nm+15)/16, 1024, 0, stream>>>(Y, Nm, Lb);
    }
  };

  // ---- Stage A ----
  k_symA<<<1, 128, 0, stream>>>(A1, Asym);
  k_buildT<<<16, 256, 0, stream>>>(Asym, Tb);
  normalize(Tb, 4096);
  // Tvy[w][(v,y)] = T[v,y,w]  (rank-16 factorized M-contractions)
  k_perm4<<<16, 256, 0, stream>>>(Tb, Tvy, 16,16,16,1, 1L,256L,16L,0L);
  k_buildM<<<256, 256, 0, stream>>>(Tb, Mb);
  normalize(Mb, 65536);
  k_initC<<<1, 256, 0, stream>>>(Mb, Ca);
  k_sym2d<<<1, 256, 0, stream>>>(Ca, 16);
  normalize(Ca, 256);
  k_initE<<<16, 256, 0, stream>>>(Mb, Ea);
  k_symE_sumsq<<<16, 256, 0, stream>>>(Ea, 16, part);
  k_scale_sumsq<<<nb256(4096), 256, 0, stream>>>(Ea, 4096, part, 16);

  // ---- CTMRG iterations ----
  const int nqs[NITER] = {8, 6, 2, 1, 1, 1, 1, 1, 1, 1, 1, 2};
  float* Ccur = Ca; float* Calt = Cb;
  float* Ecur = Ea; float* Ealt = Eb;
  float* baseB[2] = {Xa, Xb};
  int cur = 0;
  int chic = 16;
  for (int it = 0; it < NITER; ++it) {
    int Nm = chic * D2T;
    int chin = CHI;
    int nq = nqs[it];
    int coldInit = (it <= 1) ? 1 : 0;
    int doRotate = (it >= 1 && it < NITER-1) ? 1 : 0;
    int finalPasses = (it <= 1 || it == NITER-1) ? 2 : 1;
    // ---- Rho build (rank-16 factorized; perms fused into GEMM epilogues) ----
    gnn(Ccur, Ecur, CE, chic, D2T*chic, chic);                                 // CE[a,(x,i)]
    k_perm4<<<nb256((long)chic*chic*16), 256, 0, stream>>>(Ecur, E2,
        chic, chic, 16, 1, 1L, (long)16*chic, (long)chic, 0L);                 // E2[a,(j,u)]
    gtnp(CE, E2, B2, 16*chic, 16*chic, chic,
         chic, (long)chic*256, 16L, 16, 1L, 256L);                             // D1p[(i,j),(x,u)] -> B2
    gnn(B2, Tb, B3, chic*chic, 16, 256);                                       // R[ij,w] = D1p . T
    gnnp(B3, Tvy, B1, chic*chic, 256, 16,
         chic, 16L, (long)256*chic, 16, 1L, (long)16*chic);                    // m[(i,v),(j,y)] -> B1
    float* msym = B1;

    // ---- subspace eigensolve ----
    float* Xc = baseB[cur]; float* Yc = baseB[1-cur];
    if (coldInit)
      k_xinit<<<nb256((long)KSUB*Nm), 256, 0, stream>>>(Xc, KSUB*Nm, 0x9E3779B9u);
    int orthEvery = (it <= 1) ? 4 : 2;
    int since = 0;
    for (int t = 0; t < nq; ++t) {
      powmul(Xc, msym, Yc, Nm);             // Y = X m (split-K, m symmetric)
      { float* tm = Xc; Xc = Yc; Yc = tm; }
      if (++since >= orthEvery || t == nq-1) {
        ORTH(Xc, Nm, (t == nq-1) ? finalPasses : 1);
        since = 0;
      }
    }
    powmul(Xc, msym, Yc, Nm);               // Y2 = X m
    {
      int Sk = Nm >> 7;
      dim3 g(4, 4, Sk);
      k_gnt_splitk<<<g, 256, 0, stream>>>(Yc, Xc, Part, KSUB, KSUB, Nm);   // Bsm partials
      k_jacobi_post<<<1, 1024, 0, stream>>>(Part, Sk, Calt, Vsel, Vsrt, JSWMAX);
    }
    gtn(Xc, Vsel, Pb, Nm, chin, KSUB);      // P (Nm x chin) = Ritz vectors
    k_perm4<<<nb256((long)chin*Nm), 256, 0, stream>>>(Pb, Pt,
        chin, Nm, 1, 1, 1L, (long)chin, 0L, 0L);                               // Pt = Pb^T (chin x Nm)
    if (doRotate) {
      gtn(Vsrt, Xc, Yc, KSUB, Nm, KSUB);    // Xnew = Vsrt^T Xc (orthonormal rotation)
      float* tm = Xc; Xc = Yc; Yc = tm;
    }
    cur = (Xc == Xa) ? 0 : 1;

    // ---- E update (rank-16 factorized; Enew via split-K with Pt) ----
    gtnp(Pb, Ecur, B1, D2T*chin, D2T*chic, chic,
         chin, (long)chic*256, 16L, chic, 256L, 1L);                           // T1p[(a,j),(u,x)] -> B1
    gnn(B1, Tb, B3, chin*chic, 16, 256);                                       // R2[aj,w] = T1p . T
    gnnp(B3, Tvy, B2, chin*chic, 256, 16,
         chic, 16L, (long)256*chic, 16, (long)16*chic, 1L);                    // T2p[(a,y),(j,v)] -> B2
    {
      int Kd = chic * D2T;                  // K = 1536 (warm), 256 (it0)
      int Sk = Kd >> 7;
      dim3 g((chin+31)/32, (chin*D2T+31)/32, Sk);
      k_gnt_splitk<<<g, 256, 0, stream>>>(B2, Pt, B1, chin*D2T, chin, Kd);     // Enew partials -> B1
      k_reduceK<<<nb256((long)chin*D2T*chin), 256, 0, stream>>>(B1, Ealt, (long)chin*D2T*chin, Sk);
    }
    k_symE_sumsq<<<NBRED, 256, 0, stream>>>(Ealt, chin, part);
    k_scale_sumsq<<<nb256((long)chin*16*chin), 256, 0, stream>>>(Ealt, (long)chin*16*chin, part, NBRED);
    { float* t1 = Ccur; Ccur = Calt; Calt = t1; }
    { float* t1 = Ecur; Ecur = Ealt; Ealt = t1; }
    chic = chin;
  }

  // ---- Environment closure: S_env and observables ----
  gnn(Ccur, Ecur, tb, CHI, D2T*CHI, CHI);                   // t[a,(x,c)]
  gnn(tb, Ccur, ub, CHI*D2T, CHI, CHI);                     // up[(a,x),d]
  gnn(ub, Ecur, B1, CHI*D2T, D2T*CHI, CHI);                 // T1env[(a,x),(v,e)]
  k_perm4<<<nb256(SZ_BIG), 256, 0, stream>>>(B1, B2,
      16, 16, CHI, CHI, 1536L, 96L, 24576L, 1L);            // A'[(X,V),(a,e)]
  k_perm4<<<nb256(SZ_BIG), 256, 0, stream>>>(B1, B3,
      CHI, CHI, 16, 16, 1L, 24576L, 1536L, 96L);            // B'[(a,e),(Y,U)]
  gnn(B2, B3, Sb, 256, 256, CHI*CHI);                       // S[X,V,Y,U]
  k_buildK<<<4, 256, 0, stream>>>(Asym, K6);
  k_Y1<<<4, 256, 0, stream>>>(K6, Sb, Y1);
  k_W16<<<1, 16, 0, stream>>>(K6, Y1, W16);
  k_final<<<1, 1, 0, stream>>>(W16, Hin, Ox, Oy, Oz, (float*)d_out);
}

// Round 19
// 15665.501 us; speedup vs baseline: 1.5770x; 1.1272x over previous
//
#include <hip/hip_runtime.h>
#include <math.h>

#define D2T   16
#define CHI   96
#define NITER 12
#define KSUB  128
#define JSWMAX 12
#define NBRED 128

// ---------------- tiny builders ----------------
__global__ void k_symA(const float* __restrict__ A1, float* __restrict__ As) {
  int i = blockIdx.x * blockDim.x + threadIdx.x;
  if (i >= 128) return;
  int w = i % 4, x = (i / 4) % 4, u = (i / 16) % 4, p = i / 64;
#define AT(pp,aa,bb,cc) A1[(((pp)*4+(aa))*4+(bb))*4+(cc)]
  As[i] = AT(p,u,x,w) + AT(p,u,w,x) + AT(p,x,w,u) + AT(p,w,x,u) + AT(p,w,u,x) + AT(p,x,u,w);
#undef AT
}

__global__ void k_buildT(const float* __restrict__ As, float* __restrict__ T) {
  int i = blockIdx.x * blockDim.x + threadIdx.x;
  if (i >= 4096) return;
  int Wf = i % 16, Xf = (i / 16) % 16, Uf = i / 256;
  int u = Uf >> 2, a = Uf & 3, x = Xf >> 2, b = Xf & 3, w = Wf >> 2, c = Wf & 3;
  float s = 0.f;
  for (int p = 0; p < 2; ++p)
    s += As[((p*4+u)*4+x)*4+w] * As[((p*4+a)*4+b)*4+c];
  T[i] = s;
}

__global__ void k_buildM(const float* __restrict__ T, float* __restrict__ M) {
  int i = blockIdx.x * blockDim.x + threadIdx.x;
  if (i >= 65536) return;
  int y = i % 16, x = (i / 16) % 16, v = (i / 256) % 16, u = i / 4096;
  const float* Tu = T + (u*16 + x)*16;
  const float* Tv = T + (v*16 + y)*16;
  float s = 0.f;
  for (int w = 0; w < 16; ++w) s += Tu[w]*Tv[w];
  M[i] = s;
}

__global__ void k_initC(const float* __restrict__ M, float* __restrict__ C) {
  int i = blockIdx.x * blockDim.x + threadIdx.x;
  if (i >= 256) return;
  int v = i / 16, y = i % 16;
  float s = 0.f;
  for (int u = 0; u < 16; ++u)
    for (int x = 0; x < 16; ++x)
      s += M[((u*16+v)*16+x)*16+y];
  C[v*16+y] = s;
}

__global__ void k_initE(const float* __restrict__ M, float* __restrict__ E) {
  int i = blockIdx.x * blockDim.x + threadIdx.x;
  if (i >= 4096) return;
  int v = i % 16, y = (i / 16) % 16, u = i / 256;
  float s = 0.f;
  for (int x = 0; x < 16; ++x) s += M[((u*16+v)*16+x)*16+y];
  E[(u*16+y)*16+v] = s;   // E[u][y][v], chic=16
}

// ---------------- generic helpers ----------------
__global__ void k_perm4(const float* __restrict__ src, float* __restrict__ dst,
                        int d0, int d1, int d2, int d3,
                        long s0, long s1, long s2, long s3) {
  long n = (long)d0 * d1 * d2 * d3;
  for (long i = blockIdx.x * (long)blockDim.x + threadIdx.x; i < n;
       i += (long)gridDim.x * blockDim.x) {
    int i3 = (int)(i % d3); long t = i / d3;
    int i2 = (int)(t % d2); t /= d2;
    int i1 = (int)(t % d1); int i0 = (int)(t / d1);
    dst[i] = src[i0*s0 + i1*s1 + i2*s2 + i3*s3];
  }
}

__global__ void k_sym2d(float* __restrict__ A, int n) {
  long nn = (long)n * n;
  for (long i = blockIdx.x * (long)blockDim.x + threadIdx.x; i < nn;
       i += (long)gridDim.x * blockDim.x) {
    int r = (int)(i / n), c = (int)(i % n);
    if (r <= c) {
      float v = 0.5f * (A[(long)r*n + c] + A[(long)c*n + r]);
      A[(long)r*n + c] = v; A[(long)c*n + r] = v;
    }
  }
}

// fused: symmetrize E (a<=b pairs) AND accumulate ||E||^2 partials (off-diag counted twice)
__global__ void k_symE_sumsq(float* __restrict__ E, int chi, float* __restrict__ partial) {
  __shared__ float red[256];
  long n = (long)chi * 16 * chi;
  float s = 0.f;
  for (long i = blockIdx.x * (long)blockDim.x + threadIdx.x; i < n;
       i += (long)gridDim.x * blockDim.x) {
    int b = (int)(i % chi); long t = i / chi;
    int y = (int)(t % 16); int a = (int)(t / 16);
    if (a <= b) {
      long ia = ((long)a*16 + y)*chi + b, ib = ((long)b*16 + y)*chi + a;
      float v = 0.5f * (E[ia] + E[ib]);
      E[ia] = v; E[ib] = v;
      s += (a == b) ? v*v : 2.f*v*v;
    }
  }
  red[threadIdx.x] = s; __syncthreads();
  for (int o = 128; o; o >>= 1) { if ((int)threadIdx.x < o) red[threadIdx.x] += red[threadIdx.x + o]; __syncthreads(); }
  if (threadIdx.x == 0) partial[blockIdx.x] = red[0];
}

__global__ void k_sumsq(const float* __restrict__ a, long n, float* __restrict__ partial) {
  __shared__ float red[256];
  float s = 0.f;
  for (long i = blockIdx.x * 256L + threadIdx.x; i < n; i += (long)gridDim.x * 256L) {
    float v = a[i]; s += v*v;
  }
  red[threadIdx.x] = s; __syncthreads();
  for (int o = 128; o; o >>= 1) { if ((int)threadIdx.x < o) red[threadIdx.x] += red[threadIdx.x + o]; __syncthreads(); }
  if (threadIdx.x == 0) partial[blockIdx.x] = red[0];
}

__global__ void k_scale_sumsq(float* __restrict__ a, long n,
                              const float* __restrict__ partial, int nb) {
  __shared__ float red[256];
  float s = 0.f;
  for (int i = threadIdx.x; i < nb; i += 256) s += partial[i];
  red[threadIdx.x] = s; __syncthreads();
  for (int o = 128; o; o >>= 1) { if ((int)threadIdx.x < o) red[threadIdx.x] += red[threadIdx.x + o]; __syncthreads(); }
  float f = rsqrtf(red[0]);
  for (long i = blockIdx.x * (long)blockDim.x + threadIdx.x; i < n;
       i += (long)gridDim.x * blockDim.x) a[i] *= f;
}

__global__ void k_reduceK(const float* __restrict__ in, float* __restrict__ out, long mn, int S) {
  for (long i = blockIdx.x * (long)blockDim.x + threadIdx.x; i < mn;
       i += (long)gridDim.x * blockDim.x) {
    float s = 0.f;
    for (int z = 0; z < S; ++z) s += in[(long)z*mn + i];
    out[i] = s;
  }
}

// ---------------- GEMMs ----------------
// 64x64 tile, 256 thr, 4x4/thr (for well-occupied shapes)
__global__ __launch_bounds__(256) void k_gemm_nn(const float* __restrict__ A, const float* __restrict__ B,
                                                 float* __restrict__ C, int M, int N, int K) {
  __shared__ float As[16][68];
  __shared__ float Bs[16][68];
  int tid = threadIdx.x, tx = tid % 16, ty = tid / 16;
  int row0 = blockIdx.y*64, col0 = blockIdx.x*64;
  float acc[4][4] = {};
  for (int k0 = 0; k0 < K; k0 += 16) {
    for (int i = tid; i < 16*64; i += 256) {
      int c = i % 16, r = i / 16;
      float v = 0.f;
      if (row0 + r < M && k0 + c < K) v = A[(long)(row0+r)*K + k0 + c];
      As[c][r] = v;
    }
    for (int i = tid; i < 16*64; i += 256) {
      int c = i % 64, r = i / 64;
      float v = 0.f;
      if (k0 + r < K && col0 + c < N) v = B[(long)(k0+r)*N + col0 + c];
      Bs[r][c] = v;
    }
    __syncthreads();
    for (int kk = 0; kk < 16; ++kk) {
      float av[4], bv[4];
#pragma unroll
      for (int ii = 0; ii < 4; ++ii) av[ii] = As[kk][ty*4+ii];
#pragma unroll
      for (int jj = 0; jj < 4; ++jj) bv[jj] = Bs[kk][tx*4+jj];
#pragma unroll
      for (int ii = 0; ii < 4; ++ii)
#pragma unroll
        for (int jj = 0; jj < 4; ++jj) acc[ii][jj] += av[ii]*bv[jj];
    }
    __syncthreads();
  }
  for (int ii = 0; ii < 4; ++ii) {
    int r = row0 + ty*4 + ii;
    if (r >= M) continue;
    for (int jj = 0; jj < 4; ++jj) {
      int c = col0 + tx*4 + jj;
      if (c < N) C[(long)r*N + c] = acc[ii][jj];
    }
  }
}

// 32x32-tile nn (4x block count for skinny shapes; identical k-accumulation order)
__global__ __launch_bounds__(256) void k_gemm_nn32(const float* __restrict__ A, const float* __restrict__ B,
                                                   float* __restrict__ C, int M, int N, int K) {
  __shared__ float As[16][33];
  __shared__ float Bs[16][33];
  int tid = threadIdx.x, tx = tid % 16, ty = tid / 16;
  int row0 = blockIdx.y*32, col0 = blockIdx.x*32;
  float acc[2][2] = {};
  for (int k0 = 0; k0 < K; k0 += 16) {
    for (int i = tid; i < 512; i += 256) {
      int c = i & 15, r = i >> 4;
      float v = 0.f;
      if (row0 + r < M && k0 + c < K) v = A[(long)(row0+r)*K + k0 + c];
      As[c][r] = v;
    }
    for (int i = tid; i < 512; i += 256) {
      int c = i & 31, r = i >> 5;
      float v = 0.f;
      if (k0 + r < K && col0 + c < N) v = B[(long)(k0+r)*N + col0 + c];
      Bs[r][c] = v;
    }
    __syncthreads();
    for (int kk = 0; kk < 16; ++kk) {
      float a0 = As[kk][ty*2], a1 = As[kk][ty*2+1];
      float b0 = Bs[kk][tx*2], b1 = Bs[kk][tx*2+1];
      acc[0][0] += a0*b0; acc[0][1] += a0*b1;
      acc[1][0] += a1*b0; acc[1][1] += a1*b1;
    }
    __syncthreads();
  }
  for (int ii = 0; ii < 2; ++ii) {
    int r = row0 + ty*2 + ii;
    if (r >= M) continue;
    for (int jj = 0; jj < 2; ++jj) {
      int c = col0 + tx*2 + jj;
      if (c < N) C[(long)r*N + c] = acc[ii][jj];
    }
  }
}

// 32x32-tile tn: C = A^T B; A (K x M), B (K x N) row-major
__global__ __launch_bounds__(256) void k_gemm_tn32(const float* __restrict__ A, const float* __restrict__ B,
                                                   float* __restrict__ C, int M, int N, int K) {
  __shared__ float As[16][33];
  __shared__ float Bs[16][33];
  int tid = threadIdx.x, tx = tid % 16, ty = tid / 16;
  int row0 = blockIdx.y*32, col0 = blockIdx.x*32;
  float acc[2][2] = {};
  for (int k0 = 0; k0 < K; k0 += 16) {
    for (int i = tid; i < 512; i += 256) {
      int r = i & 31, kk = i >> 5;
      float v = 0.f;
      if (k0 + kk < K && row0 + r < M) v = A[(long)(k0+kk)*M + row0 + r];
      As[kk][r] = v;
    }
    for (int i = tid; i < 512; i += 256) {
      int c = i & 31, kk = i >> 5;
      float v = 0.f;
      if (k0 + kk < K && col0 + c < N) v = B[(long)(k0+kk)*N + col0 + c];
      Bs[kk][c] = v;
    }
    __syncthreads();
    for (int kk = 0; kk < 16; ++kk) {
      float a0 = As[kk][ty*2], a1 = As[kk][ty*2+1];
      float b0 = Bs[kk][tx*2], b1 = Bs[kk][tx*2+1];
      acc[0][0] += a0*b0; acc[0][1] += a0*b1;
      acc[1][0] += a1*b0; acc[1][1] += a1*b1;
    }
    __syncthreads();
  }
  for (int ii = 0; ii < 2; ++ii) {
    int r = row0 + ty*2 + ii;
    if (r >= M) continue;
    for (int jj = 0; jj < 2; ++jj) {
      int c = col0 + tx*2 + jj;
      if (c < N) C[(long)r*N + c] = acc[ii][jj];
    }
  }
}

// nn GEMM with permuted output: dst = (r%Ra)*sa + (r/Ra)*sb + (c%Cb)*sc + (c/Cb)*sd
__global__ __launch_bounds__(256) void k_gemm_nn_p(const float* __restrict__ A, const float* __restrict__ B,
                                                   float* __restrict__ C, int M, int N, int K,
                                                   int Ra, long sa, long sb, int Cb, long sc, long sd) {
  __shared__ float As[16][68];
  __shared__ float Bs[16][68];
  int tid = threadIdx.x, tx = tid % 16, ty = tid / 16;
  int row0 = blockIdx.y*64, col0 = blockIdx.x*64;
  float acc[4][4] = {};
  for (int k0 = 0; k0 < K; k0 += 16) {
    for (int i = tid; i < 16*64; i += 256) {
      int c = i % 16, r = i / 16;
      float v = 0.f;
      if (row0 + r < M && k0 + c < K) v = A[(long)(row0+r)*K + k0 + c];
      As[c][r] = v;
    }
    for (int i = tid; i < 16*64; i += 256) {
      int c = i % 64, r = i / 64;
      float v = 0.f;
      if (k0 + r < K && col0 + c < N) v = B[(long)(k0+r)*N + col0 + c];
      Bs[r][c] = v;
    }
    __syncthreads();
    for (int kk = 0; kk < 16; ++kk) {
      float av[4], bv[4];
#pragma unroll
      for (int ii = 0; ii < 4; ++ii) av[ii] = As[kk][ty*4+ii];
#pragma unroll
      for (int jj = 0; jj < 4; ++jj) bv[jj] = Bs[kk][tx*4+jj];
#pragma unroll
      for (int ii = 0; ii < 4; ++ii)
#pragma unroll
        for (int jj = 0; jj < 4; ++jj) acc[ii][jj] += av[ii]*bv[jj];
    }
    __syncthreads();
  }
  for (int ii = 0; ii < 4; ++ii) {
    int r = row0 + ty*4 + ii;
    if (r >= M) continue;
    long ro = (long)(r % Ra)*sa + (long)(r / Ra)*sb;
    for (int jj = 0; jj < 4; ++jj) {
      int c = col0 + tx*4 + jj;
      if (c < N) C[ro + (long)(c % Cb)*sc + (long)(c / Cb)*sd] = acc[ii][jj];
    }
  }
}

// tn GEMM with permuted output (same dst mapping as nn_p)
__global__ __launch_bounds__(256) void k_gemm_tn_p(const float* __restrict__ A, const float* __restrict__ B,
                                                   float* __restrict__ C, int M, int N, int K,
                                                   int Ra, long sa, long sb, int Cb, long sc, long sd) {
  __shared__ float As[16][68];
  __shared__ float Bs[16][68];
  int tid = threadIdx.x, tx = tid % 16, ty = tid / 16;
  int row0 = blockIdx.y*64, col0 = blockIdx.x*64;
  float acc[4][4] = {};
  for (int k0 = 0; k0 < K; k0 += 16) {
    for (int i = tid; i < 16*64; i += 256) {
      int r = i % 64, kk = i / 64;
      float v = 0.f;
      if (k0 + kk < K && row0 + r < M) v = A[(long)(k0+kk)*M + row0 + r];
      As[kk][r] = v;
    }
    for (int i = tid; i < 16*64; i += 256) {
      int c = i % 64, kk = i / 64;
      float v = 0.f;
      if (k0 + kk < K && col0 + c < N) v = B[(long)(k0+kk)*N + col0 + c];
      Bs[kk][c] = v;
    }
    __syncthreads();
    for (int kk = 0; kk < 16; ++kk) {
      float av[4], bv[4];
#pragma unroll
      for (int ii = 0; ii < 4; ++ii) av[ii] = As[kk][ty*4+ii];
#pragma unroll
      for (int jj = 0; jj < 4; ++jj) bv[jj] = Bs[kk][tx*4+jj];
#pragma unroll
      for (int ii = 0; ii < 4; ++ii)
#pragma unroll
        for (int jj = 0; jj < 4; ++jj) acc[ii][jj] += av[ii]*bv[jj];
    }
    __syncthreads();
  }
  for (int ii = 0; ii < 4; ++ii) {
    int r = row0 + ty*4 + ii;
    if (r >= M) continue;
    long ro = (long)(r % Ra)*sa + (long)(r / Ra)*sb;
    for (int jj = 0; jj < 4; ++jj) {
      int c = col0 + tx*4 + jj;
      if (c < N) C[ro + (long)(c % Cb)*sc + (long)(c / Cb)*sd] = acc[ii][jj];
    }
  }
}

// Split-K  Cpart[z] = A(M x K) B(N x K)^T over K-chunk z (kchunk wide). Tile 32x32, 2x2/thr.
__global__ __launch_bounds__(256) void k_gnt_splitk(const float* __restrict__ A, const float* __restrict__ B,
                                                    float* __restrict__ Cp, int M, int N, int K, int kchunk) {
  __shared__ float As[16][33];
  __shared__ float Bs[16][33];
  int tid = threadIdx.x, tx = tid % 16, ty = tid / 16;
  int row0 = blockIdx.y*32, col0 = blockIdx.x*32;
  int z = blockIdx.z;
  int kbeg = z*kchunk, kend = kbeg + kchunk < K ? kbeg + kchunk : K;
  float acc[2][2] = {};
  for (int k0 = kbeg; k0 < kend; k0 += 16) {
    for (int i = tid; i < 512; i += 256) {
      int kk = i & 15, r = i >> 4;
      float v = 0.f;
      if (row0 + r < M && k0 + kk < K) v = A[(long)(row0+r)*K + k0 + kk];
      As[kk][r] = v;
    }
    for (int i = tid; i < 512; i += 256) {
      int kk = i & 15, c = i >> 4;
      float v = 0.f;
      if (col0 + c < N && k0 + kk < K) v = B[(long)(col0+c)*K + k0 + kk];
      Bs[kk][c] = v;
    }
    __syncthreads();
    for (int kk = 0; kk < 16; ++kk) {
      float a0 = As[kk][ty*2], a1 = As[kk][ty*2+1];
      float b0 = Bs[kk][tx*2], b1 = Bs[kk][tx*2+1];
      acc[0][0] += a0*b0; acc[0][1] += a0*b1;
      acc[1][0] += a1*b0; acc[1][1] += a1*b1;
    }
    __syncthreads();
  }
  long base = (long)z * M * N;
  for (int ii = 0; ii < 2; ++ii) {
    int r = row0 + ty*2 + ii;
    if (r >= M) continue;
    for (int jj = 0; jj < 2; ++jj) {
      int c = col0 + tx*2 + jj;
      if (c < N) Cp[base + (long)r*N + c] = acc[ii][jj];
    }
  }
}

// ---------------- subspace iteration pieces ----------------
__global__ void k_xinit(float* __restrict__ X, int n, unsigned seed) {
  int i = blockIdx.x * blockDim.x + threadIdx.x;
  if (i >= n) return;
  unsigned x = (unsigned)i * 2654435761u + seed;
  x ^= x >> 16; x *= 2246822519u; x ^= x >> 13; x *= 3266489917u; x ^= x >> 16;
  X[i] = (float)x * (1.0f/4294967296.0f) - 0.5f;
}

// Reduce split-K Gram partials (128x128) -> Cholesky with clamped pivots -> Lout + flags.
__global__ __launch_bounds__(1024) void k_chol128(const float* __restrict__ Part, int nkz,
                                                  float* __restrict__ Lout) {
  __shared__ float G[128*129];
  __shared__ int flags[128];
  __shared__ float dminS;
  int tid = threadIdx.x;
  for (int i = tid; i < 16384; i += 1024) {
    float s = 0.f;
    for (int z = 0; z < nkz; ++z) s += Part[(long)z*16384 + i];
    G[(i >> 7)*129 + (i & 127)] = s;
  }
  __syncthreads();
  if (tid == 0) {
    float tr = 0.f;
    for (int i = 0; i < 128; ++i) tr += G[i*129+i];
    dminS = tr * (1e-12f/128.f) + 1e-30f;
  }
  __syncthreads();
  int ty = tid >> 5, tx = tid & 31;
  for (int k = 0; k < 128; ++k) {
    if (tid == 0) {
      float d = G[k*129+k];
      int bad = (d < dminS) ? 1 : 0;
      flags[k] = bad;
      G[k*129+k] = sqrtf(bad ? dminS : d);
    }
    __syncthreads();
    float lkk = G[k*129+k];
    int bad = flags[k];
    for (int i = k+1+tid; i < 128; i += 1024)
      G[i*129+k] = bad ? 0.f : (G[i*129+k] / lkk);
    __syncthreads();
    for (int i = k+1+ty; i < 128; i += 32)
      for (int j = k+1+tx; j <= i; j += 32)
        G[i*129+j] -= G[i*129+k] * G[j*129+k];
    __syncthreads();
  }
  for (int i = tid; i < 16384; i += 1024) Lout[i] = G[(i>>7)*129 + (i&127)];
  if (tid < 128) ((int*)Lout)[16384 + tid] = flags[tid];
}

// X (128 x Nm) <- L^{-1} X. One wave per column; L in LDS. Clamped rows re-seeded with noise.
__global__ __launch_bounds__(1024) void k_trisolve128(float* __restrict__ X, int Nm,
                                                      const float* __restrict__ Lin) {
  __shared__ float Ls[128*129];
  __shared__ int flags[128];
  int tid = threadIdx.x, wave = tid >> 6, lane = tid & 63;
  for (int i = tid; i < 16384; i += 1024) Ls[(i>>7)*129 + (i&127)] = Lin[i];
  if (tid < 128) flags[tid] = ((const int*)Lin)[16384 + tid];
  __syncthreads();
  int c = blockIdx.x*16 + wave;
  if (c >= Nm) return;
  float v0 = X[(long)lane*Nm + c];
  float v1 = X[(long)(lane+64)*Nm + c];
  for (int i = 0; i < 128; ++i) {
    float l0 = Ls[i*129 + lane];
    float l1 = Ls[i*129 + lane + 64];
    float partial = 0.f;
    if (lane < i) partial += l0 * v0;
    if (lane + 64 < i) partial += l1 * v1;
    for (int o = 32; o; o >>= 1) partial += __shfl_down(partial, o);
    float s = __shfl(partial, 0);
    float lii = Ls[i*129 + i];
    int bad = flags[i];
    unsigned h = (unsigned)(i*1315423911u) ^ (unsigned)(c*2654435761u);
    h ^= h >> 16; h *= 2246822519u; h ^= h >> 13;
    float noise = ((float)h * (1.0f/4294967296.0f) - 0.5f) * 1e-3f;
    if (i < 64) {
      if (lane == i)      v0 = bad ? noise : ((v0 - s) / lii);
    } else {
      if (lane == i - 64) v1 = bad ? noise : ((v1 - s) / lii);
    }
  }
  X[(long)lane*Nm + c] = v0;
  X[(long)(lane+64)*Nm + c] = v1;
}

// Jacobi 128x128 from split-K partials (fused reduce+symmetrize on load), early-exit,
// THRESHOLD-SKIP rounds, then fused post: |w|-select + C diag + Vsel + Vsrt.
__global__ __launch_bounds__(1024) void k_jacobi_post(const float* __restrict__ Part, int nkz,
                                                      float* __restrict__ Cmat, float* __restrict__ Vsel,
                                                      float* __restrict__ Vsrt, int maxsweeps) {
  const int n = KSUB;
  __shared__ float Bs[KSUB*KSUB];
  __shared__ float Vt[KSUB*KSUB];
  __shared__ float cS[64], sS[64];
  __shared__ int pS[64], qS[64];
  __shared__ float redA[16], redB[16];
  __shared__ int done;
  __shared__ int skipF;
  __shared__ float thrS;
  __shared__ int idxL[128];
  __shared__ float wsL[96];
  __shared__ float wsnL;
  int tid = threadIdx.x, wave = tid >> 6, lane = tid & 63;
  for (int i = tid; i < n*n; i += 1024) {
    int r = i >> 7, c = i & 127;
    float s1 = 0.f, s2 = 0.f;
    for (int z = 0; z < nkz; ++z) {
      s1 += Part[(long)z*16384 + i];
      s2 += Part[(long)z*16384 + c*128 + r];
    }
    Bs[i] = 0.5f*(s1 + s2);
    Vt[i] = (r == c) ? 1.f : 0.f;
  }
  if (tid == 0) done = 0;
  __syncthreads();
  {
    float dias = 0.f;
    for (int i = tid; i < n*n; i += 1024) {
      if ((i >> 7) == (i & 127)) { float v = Bs[i]; dias += v*v; }
    }
    for (int o = 32; o; o >>= 1) dias += __shfl_down(dias, o);
    if (lane == 0) redB[wave] = dias;
    __syncthreads();
    if (tid == 0) {
      float db = 0.f;
      for (int wv = 0; wv < 16; ++wv) db += redB[wv];
      thrS = 3e-6f * sqrtf(db / 128.f);
    }
    __syncthreads();
  }
  for (int sw = 0; sw < maxsweeps; ++sw) {
    for (int r = 0; r < n-1; ++r) {
      float myb = 0.f;
      if (tid < 64) {
        int k = tid, a, b;
        if (k == 0) { a = n-1; b = r % (n-1); }
        else { a = (r + k) % (n-1); b = (r - k + (n-1)) % (n-1); }
        int p = a < b ? a : b, q = a < b ? b : a;
        float bpp = Bs[p*n+p], bqq = Bs[q*n+q], bpq = Bs[p*n+q];
        float c = 1.f, s = 0.f;
        if (bpq != 0.f) {
          float tau = (bqq - bpp) / (2.f*bpq);
          float t = (tau >= 0.f ? 1.f : -1.f) / (fabsf(tau) + sqrtf(1.f + tau*tau));
          c = rsqrtf(1.f + t*t); s = t*c;
        }
        pS[k] = p; qS[k] = q; cS[k] = c; sS[k] = s;
        myb = fabsf(bpq);
      }
      if (tid < 64) {
        for (int o = 32; o; o >>= 1) { float ob = __shfl_down(myb, o); if (ob > myb) myb = ob; }
        if (tid == 0) skipF = (myb <= thrS) ? 1 : 0;
      }
      __syncthreads();
      if (!skipF) {
        for (int t = tid; t < 64*64; t += 1024) {
          int k1 = t >> 6, k2 = t & 63;
          int p1 = pS[k1], q1 = qS[k1]; float c1 = cS[k1], s1 = sS[k1];
          int p2 = pS[k2], q2 = qS[k2]; float c2 = cS[k2], s2 = sS[k2];
          float a = Bs[p1*n+p2], b = Bs[p1*n+q2], d = Bs[q1*n+p2], e = Bs[q1*n+q2];
          float a1 = c1*a - s1*d, b1 = c1*b - s1*e;
          float d1 = s1*a + c1*d, e1 = s1*b + c1*e;
          Bs[p1*n+p2] = c2*a1 - s2*b1; Bs[p1*n+q2] = s2*a1 + c2*b1;
          Bs[q1*n+p2] = c2*d1 - s2*e1; Bs[q1*n+q2] = s2*d1 + c2*e1;
        }
        for (int t = tid; t < 64*n; t += 1024) {
          int k = t >> 7, i = t & (n-1);
          int p = pS[k], q = qS[k]; float c = cS[k], s = sS[k];
          float vp = Vt[p*n+i], vq = Vt[q*n+i];
          Vt[p*n+i] = c*vp - s*vq; Vt[q*n+i] = s*vp + c*vq;
        }
      }
      __syncthreads();
    }
    float offs = 0.f, dias = 0.f;
    for (int i = tid; i < n*n; i += 1024) {
      float v = Bs[i];
      if ((i >> 7) == (i & 127)) dias += v*v; else offs += v*v;
    }
    for (int o = 32; o; o >>= 1) { offs += __shfl_down(offs, o); dias += __shfl_down(dias, o); }
    if (lane == 0) { redA[wave] = offs; redB[wave] = dias; }
    __syncthreads();
    if (tid == 0) {
      float oa = 0.f, db = 0.f;
      for (int wv = 0; wv < 16; ++wv) { oa += redA[wv]; db += redB[wv]; }
      done = (oa <= 1e-7f * db + 1e-30f) ? 1 : 0;
    }
    __syncthreads();
    if (done) break;
  }
  // ---- fused post: select top-|w| (wave 0), then write outputs ----
  if (tid < 64) {
    int l2 = tid;
    float v0 = Bs[l2*129], v1 = Bs[(l2+64)*129];
    float a0 = fabsf(v0), a1 = fabsf(v1);
    float ss = 0.f;
    for (int t = 0; t < n; ++t) {
      float b, bv; int bi;
      if (a0 >= a1) { b = a0; bi = l2; bv = v0; }
      else          { b = a1; bi = l2 + 64; bv = v1; }
      for (int o = 32; o; o >>= 1) {
        float ob = __shfl_down(b, o);
        int   oi = __shfl_down(bi, o);
        float ov = __shfl_down(bv, o);
        if (ob > b) { b = ob; bi = oi; bv = ov; }
      }
      bi = __shfl(bi, 0); bv = __shfl(bv, 0);
      if (l2 == 0) {
        idxL[t] = bi;
        if (t < 96) { wsL[t] = bv; ss += bv * bv; }
      }
      if (bi == l2) a0 = -1.f;
      if (bi == l2 + 64) a1 = -1.f;
    }
    if (l2 == 0) wsnL = sqrtf(ss);
  }
  __syncthreads();
  float invn = 1.f / wsnL;
  for (int i = tid; i < 96*96; i += 1024) {
    int r = i / 96, c = i % 96;
    Cmat[i] = (r == c) ? wsL[r] * invn : 0.f;
  }
  for (int i = tid; i < 128*96; i += 1024) {
    int q = i / 96, a = i % 96;
    Vsel[i] = Vt[idxL[a]*n + q];
  }
  for (int i = tid; i < 128*128; i += 1024) {
    int q = i >> 7, t = i & 127;
    Vsrt[i] = Vt[idxL[t]*n + q];
  }
}

// ---------------- observable stage ----------------
__global__ void k_buildK(const float* __restrict__ As, float* __restrict__ K6) {
  int i = blockIdx.x * blockDim.x + threadIdx.x;
  if (i >= 1024) return;
  int y = i & 3, v = (i>>2)&3, x = (i>>4)&3, u = (i>>6)&3, s = (i>>8)&1, p = (i>>9)&1;
  float acc = 0.f;
  for (int w = 0; w < 4; ++w)
    acc += As[((p*4+u)*4+x)*4+w] * As[((s*4+v)*4+y)*4+w];
  K6[i] = acc;
}

__global__ void k_Y1(const float* __restrict__ K6, const float* __restrict__ S, float* __restrict__ Y1) {
  int i = blockIdx.x * blockDim.x + threadIdx.x;
  if (i >= 1024) return;
  int f = i & 3, e = (i>>2)&3, b = (i>>4)&3, a = (i>>6)&3, s = (i>>8)&1, p = (i>>9)&1;
  float acc = 0.f;
  for (int u = 0; u < 4; ++u)
    for (int x = 0; x < 4; ++x)
      for (int v = 0; v < 4; ++v)
        for (int y = 0; y < 4; ++y)
          acc += K6[((((p*2+s)*4+u)*4+x)*4+v)*4+y]
               * S[(((x*4+b)*16 + (v*4+e))*16 + (y*4+f))*16 + (u*4+a)];
  Y1[i] = acc;
}

__global__ void k_W16(const float* __restrict__ K6, const float* __restrict__ Y1, float* __restrict__ W) {
  int i = threadIdx.x;
  if (i >= 16) return;
  int qr = i >> 2, ps = i & 3;
  float acc = 0.f;
  for (int j = 0; j < 256; ++j) acc += K6[qr*256 + j] * Y1[ps*256 + j];
  W[i] = acc;
}

__global__ void k_final(const float* __restrict__ W, const float* __restrict__ H,
                        const float* __restrict__ Ox, const float* __restrict__ Oy,
                        const float* __restrict__ Oz, float* __restrict__ out) {
  if (threadIdx.x != 0 || blockIdx.x != 0) return;
  float Z = 0.f;
  for (int q = 0; q < 2; ++q)
    for (int r = 0; r < 2; ++r) Z += W[((q*2+r)*2+q)*2+r];
  float ln = 0.f;
  for (int i = 0; i < 16; ++i) ln += H[i]*W[i];
  out[0] = ln / Z;
  const float* Os[3] = {Ox, Oy, Oz};
  for (int k = 0; k < 3; ++k) {
    float vA = 0.f, vB = 0.f;
    for (int q = 0; q < 2; ++q)
      for (int p = 0; p < 2; ++p)
        for (int r = 0; r < 2; ++r)
          vA += Os[k][q*2+p] * W[((q*2+r)*2+p)*2+r];
    for (int q = 0; q < 2; ++q)
      for (int r = 0; r < 2; ++r)
        for (int s = 0; s < 2; ++s)
          vB += Os[k][r*2+s] * W[((q*2+r)*2+q)*2+s];
    out[1+k] = 0.5f*(vA+vB)/Z;
  }
}

// ---------------- host ----------------
static inline unsigned nb256(long n) { long b = (n + 255) / 256; return (unsigned)(b < 1 ? 1 : b); }

extern "C" void kernel_launch(void* const* d_in, const int* in_sizes, int n_in,
                              void* d_out, int out_size, void* d_ws, size_t ws_size,
                              hipStream_t stream) {
  const float* A1  = (const float*)d_in[0];
  const float* Hin = (const float*)d_in[1];
  const float* Ox  = (const float*)d_in[2];
  const float* Oy  = (const float*)d_in[3];
  const float* Oz  = (const float*)d_in[4];

  const long SZ_BIG = 1536L*1536L;
  float* p0 = (float*)d_ws;
  float* Asym = p0; p0 += 128;
  float* Tb   = p0; p0 += 4096;
  float* Tvy  = p0; p0 += 4096;
  float* Mb   = p0; p0 += 65536;
  float* Ca   = p0; p0 += CHI*CHI;
  float* Cb   = p0; p0 += CHI*CHI;
  float* Ea   = p0; p0 += CHI*D2T*CHI;
  float* Eb   = p0; p0 += CHI*D2T*CHI;
  float* CE   = p0; p0 += CHI*D2T*CHI;
  float* E2   = p0; p0 += CHI*D2T*CHI;
  float* Pb   = p0; p0 += (CHI*D2T)*CHI;
  float* Pt   = p0; p0 += CHI*(CHI*D2T);
  float* Xa   = p0; p0 += KSUB*(CHI*D2T);
  float* Xb   = p0; p0 += KSUB*(CHI*D2T);
  float* Vsrt = p0; p0 += KSUB*KSUB;
  float* Lb   = p0; p0 += 16384 + 128;
  float* Part = p0; p0 += 12*65536;        // split-K partials (enlarged for Sb: 12 x 256x256)
  float* part = p0; p0 += NBRED;
  float* Vsel = p0; p0 += KSUB*CHI;
  float* K6   = p0; p0 += 1024;
  float* Y1   = p0; p0 += 1024;
  float* W16  = p0; p0 += 16;
  float* tb   = p0; p0 += CHI*D2T*CHI;
  float* ub   = p0; p0 += CHI*D2T*CHI;
  float* Sb   = p0; p0 += 65536;
  float* B1   = p0; p0 += SZ_BIG;
  float* B2   = p0; p0 += SZ_BIG;
  float* B3   = p0; p0 += SZ_BIG;
  if ((size_t)((char*)p0 - (char*)d_ws) > ws_size) return;

  auto normalize = [&](float* a, long n) {
    int nb = (int)((n + 255) / 256); if (nb > NBRED) nb = NBRED;
    k_sumsq<<<nb, 256, 0, stream>>>(a, n, part);
    k_scale_sumsq<<<nb256(n), 256, 0, stream>>>(a, n, part, nb);
  };
  auto gnn = [&](const float* A, const float* B, float* C, int M, int N, int K) {
    dim3 g((N+63)/64, (M+63)/64);
    k_gemm_nn<<<g, 256, 0, stream>>>(A, B, C, M, N, K);
  };
  auto gnn32 = [&](const float* A, const float* B, float* C, int M, int N, int K) {
    dim3 g((N+31)/32, (M+31)/32);
    k_gemm_nn32<<<g, 256, 0, stream>>>(A, B, C, M, N, K);
  };
  auto gtn32 = [&](const float* A, const float* B, float* C, int M, int N, int K) {
    dim3 g((N+31)/32, (M+31)/32);
    k_gemm_tn32<<<g, 256, 0, stream>>>(A, B, C, M, N, K);
  };
  auto gnnp = [&](const float* A, const float* B, float* C, int M, int N, int K,
                  int Ra, long sa, long sb, int Cbb, long sc, long sd) {
    dim3 g((N+63)/64, (M+63)/64);
    k_gemm_nn_p<<<g, 256, 0, stream>>>(A, B, C, M, N, K, Ra, sa, sb, Cbb, sc, sd);
  };
  auto gtnp = [&](const float* A, const float* B, float* C, int M, int N, int K,
                  int Ra, long sa, long sb, int Cbb, long sc, long sd) {
    dim3 g((N+63)/64, (M+63)/64);
    k_gemm_tn_p<<<g, 256, 0, stream>>>(A, B, C, M, N, K, Ra, sa, sb, Cbb, sc, sd);
  };
  // Power multiply Y = X * m via split-K NT (m symmetric => X*m = X*m^T).
  auto powmul = [&](const float* X, const float* m, float* Y, int Nm) {
    int Sk = Nm >> 7;
    dim3 g(Nm/32, 4, Sk);
    k_gnt_splitk<<<g, 256, 0, stream>>>(X, m, B2, KSUB, Nm, Nm, 128);
    k_reduceK<<<nb256((long)KSUB*Nm), 256, 0, stream>>>(B2, Y, (long)KSUB*Nm, Sk);
  };
  // Full-basis CholQR: `passes` x (split-K Gram -> chol128 -> trisolve).
  auto ORTH = [&](float* Y, int Nm, int passes) {
    int Sk = Nm >> 7;
    for (int pass = 0; pass < passes; ++pass) {
      dim3 g(4, 4, Sk);
      k_gnt_splitk<<<g, 256, 0, stream>>>(Y, Y, Part, KSUB, KSUB, Nm, 128);
      k_chol128<<<1, 1024, 0, stream>>>(Part, Sk, Lb);
      k_trisolve128<<<(Nm+15)/16, 1024, 0, stream>>>(Y, Nm, Lb);
    }
  };

  // ---- Stage A ----
  k_symA<<<1, 128, 0, stream>>>(A1, Asym);
  k_buildT<<<16, 256, 0, stream>>>(Asym, Tb);
  normalize(Tb, 4096);
  // Tvy[w][(v,y)] = T[v,y,w]  (rank-16 factorized M-contractions)
  k_perm4<<<16, 256, 0, stream>>>(Tb, Tvy, 16,16,16,1, 1L,256L,16L,0L);
  k_buildM<<<256, 256, 0, stream>>>(Tb, Mb);
  normalize(Mb, 65536);
  k_initC<<<1, 256, 0, stream>>>(Mb, Ca);
  k_sym2d<<<1, 256, 0, stream>>>(Ca, 16);
  normalize(Ca, 256);
  k_initE<<<16, 256, 0, stream>>>(Mb, Ea);
  k_symE_sumsq<<<16, 256, 0, stream>>>(Ea, 16, part);
  k_scale_sumsq<<<nb256(4096), 256, 0, stream>>>(Ea, 4096, part, 16);

  // ---- CTMRG iterations ----
  const int nqs[NITER] = {8, 6, 2, 1, 1, 1, 1, 1, 1, 1, 1, 2};
  float* Ccur = Ca; float* Calt = Cb;
  float* Ecur = Ea; float* Ealt = Eb;
  float* baseB[2] = {Xa, Xb};
  int cur = 0;
  int chic = 16;
  for (int it = 0; it < NITER; ++it) {
    int Nm = chic * D2T;
    int chin = CHI;
    int nq = nqs[it];
    int coldInit = (it <= 1) ? 1 : 0;
    int doRotate = (it >= 1 && it < NITER-1) ? 1 : 0;
    int finalPasses = (it <= 1 || it == NITER-1) ? 2 : 1;
    // ---- Rho build (rank-16 factorized; 32-tile for skinny shapes) ----
    gnn32(Ccur, Ecur, CE, chic, D2T*chic, chic);                               // CE[a,(x,i)]
    k_perm4<<<nb256((long)chic*chic*16), 256, 0, stream>>>(Ecur, E2,
        chic, chic, 16, 1, 1L, (long)16*chic, (long)chic, 0L);                 // E2[a,(j,u)]
    gtnp(CE, E2, B2, 16*chic, 16*chic, chic,
         chic, (long)chic*256, 16L, 16, 1L, 256L);                             // D1p[(i,j),(x,u)] -> B2
    gnn32(B2, Tb, B3, chic*chic, 16, 256);                                     // R[ij,w] = D1p . T
    gnnp(B3, Tvy, B1, chic*chic, 256, 16,
         chic, 16L, (long)256*chic, 16, 1L, (long)16*chic);                    // m[(i,v),(j,y)] -> B1
    float* msym = B1;

    // ---- subspace eigensolve ----
    float* Xc = baseB[cur]; float* Yc = baseB[1-cur];
    if (coldInit)
      k_xinit<<<nb256((long)KSUB*Nm), 256, 0, stream>>>(Xc, KSUB*Nm, 0x9E3779B9u);
    int orthEvery = (it <= 1) ? 4 : 2;
    int since = 0;
    for (int t = 0; t < nq; ++t) {
      powmul(Xc, msym, Yc, Nm);             // Y = X m (split-K, m symmetric)
      { float* tm = Xc; Xc = Yc; Yc = tm; }
      if (++since >= orthEvery || t == nq-1) {
        ORTH(Xc, Nm, (t == nq-1) ? finalPasses : 1);
        since = 0;
      }
    }
    powmul(Xc, msym, Yc, Nm);               // Y2 = X m
    {
      int Sk = Nm >> 7;
      dim3 g(4, 4, Sk);
      k_gnt_splitk<<<g, 256, 0, stream>>>(Yc, Xc, Part, KSUB, KSUB, Nm, 128); // Bsm partials
      k_jacobi_post<<<1, 1024, 0, stream>>>(Part, Sk, Calt, Vsel, Vsrt, JSWMAX);
    }
    gtn32(Xc, Vsel, Pb, Nm, chin, KSUB);    // P (Nm x chin) = Ritz vectors
    k_perm4<<<nb256((long)chin*Nm), 256, 0, stream>>>(Pb, Pt,
        chin, Nm, 1, 1, 1L, (long)chin, 0L, 0L);                               // Pt = Pb^T (chin x Nm)
    if (doRotate) {
      gtn32(Vsrt, Xc, Yc, KSUB, Nm, KSUB);  // Xnew = Vsrt^T Xc (orthonormal rotation)
      float* tm = Xc; Xc = Yc; Yc = tm;
    }
    cur = (Xc == Xa) ? 0 : 1;

    // ---- E update (rank-16 factorized; Enew via split-K with Pt) ----
    gtnp(Pb, Ecur, B1, D2T*chin, D2T*chic, chic,
         chin, (long)chic*256, 16L, chic, 256L, 1L);                           // T1p[(a,j),(u,x)] -> B1
    gnn32(B1, Tb, B3, chin*chic, 16, 256);                                     // R2[aj,w] = T1p . T
    gnnp(B3, Tvy, B2, chin*chic, 256, 16,
         chic, 16L, (long)256*chic, 16, (long)16*chic, 1L);                    // T2p[(a,y),(j,v)] -> B2
    {
      int Kd = chic * D2T;                  // K = 1536 (warm), 256 (it0)
      int Sk = Kd >> 7;
      dim3 g((chin+31)/32, (chin*D2T+31)/32, Sk);
      k_gnt_splitk<<<g, 256, 0, stream>>>(B2, Pt, B1, chin*D2T, chin, Kd, 128); // Enew partials -> B1
      k_reduceK<<<nb256((long)chin*D2T*chin), 256, 0, stream>>>(B1, Ealt, (long)chin*D2T*chin, Sk);
    }
    k_symE_sumsq<<<NBRED, 256, 0, stream>>>(Ealt, chin, part);
    k_scale_sumsq<<<nb256((long)chin*16*chin), 256, 0, stream>>>(Ealt, (long)chin*16*chin, part, NBRED);
    { float* t1 = Ccur; Ccur = Calt; Calt = t1; }
    { float* t1 = Ecur; Ecur = Ealt; Ealt = t1; }
    chic = chin;
  }

  // ---- Environment closure: S_env and observables ----
  gnn32(Ccur, Ecur, tb, CHI, D2T*CHI, CHI);                 // t[a,(x,c)]
  gnn32(tb, Ccur, ub, CHI*D2T, CHI, CHI);                   // up[(a,x),d]
  gnn(ub, Ecur, B1, CHI*D2T, D2T*CHI, CHI);                 // T1env[(a,x),(v,e)]
  k_perm4<<<nb256(SZ_BIG), 256, 0, stream>>>(B1, B2,
      16, 16, CHI, CHI, 1536L, 96L, 24576L, 1L);            // A'[(X,V),(a,e)]
  k_perm4<<<nb256(SZ_BIG), 256, 0, stream>>>(B1, B3,
      16, 16, CHI, CHI, 1536L, 96L, 1L, 24576L);            // B'^T[(Y,U),(a,e)]
  {
    // S = A' . B' = A' . (B'^T)^T via chunked split-K: grid (8,8,12)
    dim3 g(8, 8, 12);
    k_gnt_splitk<<<g, 256, 0, stream>>>(B2, B3, Part, 256, 256, CHI*CHI, 768);
    k_reduceK<<<nb256(65536L), 256, 0, stream>>>(Part, Sb, 65536L, 12);
  }
  k_buildK<<<4, 256, 0, stream>>>(Asym, K6);
  k_Y1<<<4, 256, 0, stream>>>(K6, Sb, Y1);
  k_W16<<<1, 16, 0, stream>>>(K6, Y1, W16);
  k_final<<<1, 1, 0, stream>>>(W16, Hin, Ox, Oy, Oz, (float*)d_out);
}